// Round 11
// baseline (192.218 us; speedup 1.0000x reference)
//
#include <hip/hip_runtime.h>
#include <hip/hip_bf16.h>
#include <math.h>

#define NEGV -9e15f

typedef short bf16x8 __attribute__((ext_vector_type(8)));
typedef float f32x4 __attribute__((ext_vector_type(4)));

__device__ __forceinline__ unsigned short f2bf(float x) {
  unsigned u = __float_as_uint(x);
  u += 0x7fffu + ((u >> 16) & 1u);
  return (unsigned short)(u >> 16);
}

__device__ __forceinline__ unsigned pk2(float a, float b) {
  __hip_bfloat162 h = __float22bfloat162_rn(make_float2(a, b));
  unsigned u;
  __builtin_memcpy(&u, &h, 4);
  return u;
}

// branchless mish: x * n/(n+2), n = u(u+2), u = e^min(x,30)
__device__ __forceinline__ float mishf(float x) {
  float u = __expf(fminf(x, 30.0f));
  float n = u * (u + 2.0f);
  return x * __fdividef(n, n + 2.0f);
}

// ---------------- prep: svec rows (bid<1024) + M composite rows (bid>=1024) ----------------
__global__ void prep_kernel(const float* __restrict__ v, float* __restrict__ s,
                            const float* __restrict__ Wb, const float* __restrict__ bb,
                            const float* __restrict__ Wo, float* __restrict__ M) {
  int bid = blockIdx.x;
  int lane = threadIdx.x;  // 64
  if (bid < 1024) {
    float4 a = *reinterpret_cast<const float4*>(v + (size_t)bid * 256 + lane * 4);
    float x = a.x + a.y + a.z + a.w;
    for (int off = 32; off; off >>= 1) x += __shfl_down(x, off);
    if (lane == 0) s[bid] = x;
  } else {
    int i = bid - 1024;  // 0..40
    if (lane >= 40) return;
    float acc = 0.0f;
    for (int k = 0; k < 160; ++k) {
      float w = (i < 40) ? Wb[i * 160 + k] : bb[k];
      acc = fmaf(w, Wo[k * 40 + lane], acc);
    }
    M[i * 40 + lane] = acc;
  }
}

// ---------------- paired GEMM: z selects (A,W,bvec,C); C = A @ W(perm) + bvec ----------------
__global__ __launch_bounds__(256) void gemm_pair(
    const float* __restrict__ A0, const float* __restrict__ W0,
    const float* __restrict__ bv0, float* __restrict__ C0,
    const float* __restrict__ A1, const float* __restrict__ W1,
    const float* __restrict__ bv1, float* __restrict__ C1, int perm) {
  const float* A = blockIdx.z ? A1 : A0;
  const float* W = blockIdx.z ? W1 : W0;
  const float* bvec = blockIdx.z ? bv1 : bv0;
  float* C = blockIdx.z ? C1 : C0;
  __shared__ float sAT[16][68];
  __shared__ float sW[16][68];
  int tid = threadIdx.x;
  int c0 = blockIdx.x * 64, r0 = blockIdx.y * 64;
  int ty = tid >> 4, tx = tid & 15;
  float acc[4][4] = {};
  for (int k0 = 0; k0 < 256; k0 += 16) {
    {
      int r = tid >> 2, jq = tid & 3;
      float4 a4 = *reinterpret_cast<const float4*>(A + (size_t)(r0 + r) * 256 + k0 + jq * 4);
      sAT[jq * 4 + 0][r] = a4.x;
      sAT[jq * 4 + 1][r] = a4.y;
      sAT[jq * 4 + 2][r] = a4.z;
      sAT[jq * 4 + 3][r] = a4.w;
    }
    {
      int kk = tid >> 4, cq = tid & 15;
      int gk = k0 + kk;
      int row = perm ? ((gk & 63) * 4 + (gk >> 6)) : gk;
      float4 w4 = *reinterpret_cast<const float4*>(W + (size_t)row * 256 + c0 + cq * 4);
      *reinterpret_cast<float4*>(&sW[kk][cq * 4]) = w4;
    }
    __syncthreads();
#pragma unroll
    for (int kk = 0; kk < 16; ++kk) {
      float4 av = *reinterpret_cast<const float4*>(&sAT[kk][ty * 4]);
      float4 bv = *reinterpret_cast<const float4*>(&sW[kk][tx * 4]);
      float a[4] = {av.x, av.y, av.z, av.w};
      float b[4] = {bv.x, bv.y, bv.z, bv.w};
#pragma unroll
      for (int i = 0; i < 4; ++i)
#pragma unroll
        for (int j = 0; j < 4; ++j) acc[i][j] = fmaf(a[i], b[j], acc[i][j]);
    }
    __syncthreads();
  }
#pragma unroll
  for (int i = 0; i < 4; ++i) {
    int rr = r0 + ty * 4 + i, cc = c0 + tx * 4;
    float4 o;
    o.x = acc[i][0] + bvec[cc + 0];
    o.y = acc[i][1] + bvec[cc + 1];
    o.z = acc[i][2] + bvec[cc + 2];
    o.w = acc[i][3] + bvec[cc + 3];
    *reinterpret_cast<float4*>(C + (size_t)rr * 256 + cc) = o;
  }
}

// ---------------- paired LN: out = LN(x0 + mish(y)) * g + be; y selects q/k ----------------
__global__ __launch_bounds__(256) void ln_pair(
    const float* __restrict__ x0q, const float* __restrict__ yq,
    const float* __restrict__ gq, const float* __restrict__ beq,
    float* __restrict__ outq,
    const float* __restrict__ x0k, const float* __restrict__ yk,
    const float* __restrict__ gk, const float* __restrict__ bek,
    float* __restrict__ outk) {
  const float* x0 = blockIdx.y ? x0k : x0q;
  const float* y  = blockIdx.y ? yk  : yq;
  const float* g  = blockIdx.y ? gk  : gq;
  const float* be = blockIdx.y ? bek : beq;
  float* out      = blockIdx.y ? outk : outq;
  __shared__ float r1[5], r2[5];
  int r = blockIdx.x, t = threadIdx.x;
  int wid = t >> 6, lane = t & 63;
  float x = x0[(size_t)r * 256 + t] + mishf(y[(size_t)r * 256 + t]);
  float a = x, b = x * x;
  for (int off = 32; off; off >>= 1) {
    a += __shfl_down(a, off);
    b += __shfl_down(b, off);
  }
  if (lane == 0) { r1[wid] = a; r2[wid] = b; }
  __syncthreads();
  if (t == 0) {
    r1[4] = r1[0] + r1[1] + r1[2] + r1[3];
    r2[4] = r2[0] + r2[1] + r2[2] + r2[3];
  }
  __syncthreads();
  float m = r1[4] * (1.0f / 256.0f);
  float var = r2[4] * (1.0f / 256.0f) - m * m;
  out[(size_t)r * 256 + t] = (x - m) * rsqrtf(var + 1e-5f) * g[t] + be[t];
}

// ---------------- fused bias path v3: regs-only, 2 tiles/iter (NT stores for bout) ----------------
#define TILE_BODY(XF0, XF1, P0) do {                                                   \
    float hv0, hv1, hv2, hv3;                                                          \
    {                                                                                  \
      f32x4 z = {0.0f, 0.0f, 0.0f, 0.0f};                                              \
      f32x4 q;                                                                         \
      float cs2, cs7;                                                                  \
      q = __builtin_amdgcn_mfma_f32_16x16x32_bf16(wf[0][0], XF0, z, 0, 0, 0);          \
      q = __builtin_amdgcn_mfma_f32_16x16x32_bf16(wf[0][1], XF1, q, 0, 0, 0);          \
      hv0 = q[0]*q[0] + q[1]*q[1] + q[2]*q[2] + q[3]*q[3];                             \
      q = __builtin_amdgcn_mfma_f32_16x16x32_bf16(wf[1][0], XF0, z, 0, 0, 0);          \
      q = __builtin_amdgcn_mfma_f32_16x16x32_bf16(wf[1][1], XF1, q, 0, 0, 0);          \
      hv0 += q[0]*q[0] + q[1]*q[1] + q[2]*q[2] + q[3]*q[3];                            \
      q = __builtin_amdgcn_mfma_f32_16x16x32_bf16(wf[2][0], XF0, z, 0, 0, 0);          \
      q = __builtin_amdgcn_mfma_f32_16x16x32_bf16(wf[2][1], XF1, q, 0, 0, 0);          \
      cs2 = q[0]*q[0] + q[1]*q[1] + q[2]*q[2] + q[3]*q[3];                             \
      q = __builtin_amdgcn_mfma_f32_16x16x32_bf16(wf[3][0], XF0, z, 0, 0, 0);          \
      q = __builtin_amdgcn_mfma_f32_16x16x32_bf16(wf[3][1], XF1, q, 0, 0, 0);          \
      hv1 = q[0]*q[0] + q[1]*q[1] + q[2]*q[2] + q[3]*q[3];                             \
      q = __builtin_amdgcn_mfma_f32_16x16x32_bf16(wf[4][0], XF0, z, 0, 0, 0);          \
      q = __builtin_amdgcn_mfma_f32_16x16x32_bf16(wf[4][1], XF1, q, 0, 0, 0);          \
      hv1 += q[0]*q[0] + q[1]*q[1] + q[2]*q[2] + q[3]*q[3];                            \
      q = __builtin_amdgcn_mfma_f32_16x16x32_bf16(wf[5][0], XF0, z, 0, 0, 0);          \
      q = __builtin_amdgcn_mfma_f32_16x16x32_bf16(wf[5][1], XF1, q, 0, 0, 0);          \
      hv2 = q[0]*q[0] + q[1]*q[1] + q[2]*q[2] + q[3]*q[3];                             \
      q = __builtin_amdgcn_mfma_f32_16x16x32_bf16(wf[6][0], XF0, z, 0, 0, 0);          \
      q = __builtin_amdgcn_mfma_f32_16x16x32_bf16(wf[6][1], XF1, q, 0, 0, 0);          \
      hv2 += q[0]*q[0] + q[1]*q[1] + q[2]*q[2] + q[3]*q[3];                            \
      q = __builtin_amdgcn_mfma_f32_16x16x32_bf16(wf[7][0], XF0, z, 0, 0, 0);          \
      q = __builtin_amdgcn_mfma_f32_16x16x32_bf16(wf[7][1], XF1, q, 0, 0, 0);          \
      cs7 = q[0]*q[0] + q[1]*q[1] + q[2]*q[2] + q[3]*q[3];                             \
      q = __builtin_amdgcn_mfma_f32_16x16x32_bf16(wf[8][0], XF0, z, 0, 0, 0);          \
      q = __builtin_amdgcn_mfma_f32_16x16x32_bf16(wf[8][1], XF1, q, 0, 0, 0);          \
      hv3 = q[0]*q[0] + q[1]*q[1] + q[2]*q[2] + q[3]*q[3];                             \
      q = __builtin_amdgcn_mfma_f32_16x16x32_bf16(wf[9][0], XF0, z, 0, 0, 0);          \
      q = __builtin_amdgcn_mfma_f32_16x16x32_bf16(wf[9][1], XF1, q, 0, 0, 0);          \
      hv3 += q[0]*q[0] + q[1]*q[1] + q[2]*q[2] + q[3]*q[3];                            \
      float csa = (g < 2) ? cs2 : 0.0f;                                                \
      float csb = (g < 2) ? 0.0f : cs2;                                                \
      float csc = (g < 2) ? cs7 : 0.0f;                                                \
      float csd = (g < 2) ? 0.0f : cs7;                                                \
      hv0 += csa; hv1 += csb; hv2 += csc; hv3 += csd;                                  \
    }                                                                                  \
    hv0 += __shfl_xor(hv0, 16); hv0 += __shfl_xor(hv0, 32);                            \
    hv1 += __shfl_xor(hv1, 16); hv1 += __shfl_xor(hv1, 32);                            \
    hv2 += __shfl_xor(hv2, 16); hv2 += __shfl_xor(hv2, 32);                            \
    hv3 += __shfl_xor(hv3, 16); hv3 += __shfl_xor(hv3, 32);                            \
    float ss = (g == 0) ? hv0 : (g == 1) ? hv1 : (g == 2) ? hv2 : hv3;                 \
    diffs[(size_t)g * (1024 * 1024) + (P0) + r] = sqrtf(ss);                           \
    f32x4 o0 = bo40, o1 = bo41, o2 = bo42;                                             \
    o0 = __builtin_amdgcn_mfma_f32_16x16x32_bf16(mf[0][0], XF0, o0, 0, 0, 0);          \
    o1 = __builtin_amdgcn_mfma_f32_16x16x32_bf16(mf[1][0], XF0, o1, 0, 0, 0);          \
    o2 = __builtin_amdgcn_mfma_f32_16x16x32_bf16(mf[2][0], XF0, o2, 0, 0, 0);          \
    o0 = __builtin_amdgcn_mfma_f32_16x16x32_bf16(mf[0][1], XF1, o0, 0, 0, 0);          \
    o1 = __builtin_amdgcn_mfma_f32_16x16x32_bf16(mf[1][1], XF1, o1, 0, 0, 0);          \
    o2 = __builtin_amdgcn_mfma_f32_16x16x32_bf16(mf[2][1], XF1, o2, 0, 0, 0);          \
    float* bp = bout + (size_t)((P0) + r) * 40;                                        \
    f32x4 stv;                                                                         \
    stv[0] = mishf(o0[0]); stv[1] = mishf(o0[1]);                                      \
    stv[2] = mishf(o0[2]); stv[3] = mishf(o0[3]);                                      \
    __builtin_nontemporal_store(stv, reinterpret_cast<f32x4*>(bp + 4 * g));            \
    stv[0] = mishf(o1[0]); stv[1] = mishf(o1[1]);                                      \
    stv[2] = mishf(o1[2]); stv[3] = mishf(o1[3]);                                      \
    __builtin_nontemporal_store(stv, reinterpret_cast<f32x4*>(bp + 16 + 4 * g));       \
    if (g < 2) {                                                                       \
      stv[0] = mishf(o2[0]); stv[1] = mishf(o2[1]);                                    \
      stv[2] = mishf(o2[2]); stv[3] = mishf(o2[3]);                                    \
      __builtin_nontemporal_store(stv, reinterpret_cast<f32x4*>(bp + 32 + 4 * g));     \
    }                                                                                  \
  } while (0)

__global__ __launch_bounds__(256, 2) void bias_mfma(
    const float* __restrict__ bias, const float* __restrict__ Wb,
    const float* __restrict__ bb, const float* __restrict__ Mmat,
    const float* __restrict__ bo, float* __restrict__ diffs,
    float* __restrict__ bout) {
  int tid = threadIdx.x;
  int wv = tid >> 6, lane = tid & 63;
  int r = lane & 15, g = lane >> 4;

  // Wb' fragments (A-operand): wf[n0][ks]; k=40 slot carries bb (bias fold)
  bf16x8 wf[10][2];
#pragma unroll
  for (int n0 = 0; n0 < 10; ++n0)
#pragma unroll
    for (int ks = 0; ks < 2; ++ks)
#pragma unroll
      for (int jj = 0; jj < 8; ++jj) {
        int k = ks * 32 + g * 8 + jj;
        int c = n0 * 16 + r;
        float w = (k < 40) ? Wb[k * 160 + c] : ((k == 40) ? bb[c] : 0.0f);
        wf[n0][ks][jj] = (short)f2bf(w);
      }
  // M^T fragments (A-operand): mf[n][ks]
  bf16x8 mf[3][2];
#pragma unroll
  for (int n = 0; n < 3; ++n)
#pragma unroll
    for (int ks = 0; ks < 2; ++ks)
#pragma unroll
      for (int jj = 0; jj < 8; ++jj) {
        int k = ks * 32 + g * 8 + jj;
        int c = n * 16 + r;
        float w = (k <= 40 && c < 40) ? Mmat[k * 40 + c] : 0.0f;
        mf[n][ks][jj] = (short)f2bf(w);
      }
  // bo as per-lane f32x4: cols 16n + 4g .. +3
  f32x4 bo40, bo41, bo42;
  {
    float4 t0 = *reinterpret_cast<const float4*>(bo + 4 * g);
    float4 t1 = *reinterpret_cast<const float4*>(bo + 16 + 4 * g);
    bo40[0] = t0.x; bo40[1] = t0.y; bo40[2] = t0.z; bo40[3] = t0.w;
    bo41[0] = t1.x; bo41[1] = t1.y; bo41[2] = t1.z; bo41[3] = t1.w;
    if (g < 2) {
      float4 t2 = *reinterpret_cast<const float4*>(bo + 32 + 4 * g);
      bo42[0] = t2.x; bo42[1] = t2.y; bo42[2] = t2.z; bo42[3] = t2.w;
    } else {
      bo42[0] = 0.0f; bo42[1] = 0.0f; bo42[2] = 0.0f; bo42[3] = 0.0f;
    }
  }

  size_t row0 = ((size_t)blockIdx.x * 4 + wv) * 256;  // 8 iters x 2 tiles x 16 rows

  // prefetch tiles 0,1
  const float* xr0 = bias + (row0 + r) * 40;
  const float* xr1 = bias + (row0 + 16 + r) * 40;
  float4 x0A = *reinterpret_cast<const float4*>(xr0 + g * 8);
  float4 x0B = *reinterpret_cast<const float4*>(xr0 + g * 8 + 4);
  float4 x0C = *reinterpret_cast<const float4*>(xr0 + 32);
  float4 x0D = *reinterpret_cast<const float4*>(xr0 + 36);
  float4 x1A = *reinterpret_cast<const float4*>(xr1 + g * 8);
  float4 x1B = *reinterpret_cast<const float4*>(xr1 + g * 8 + 4);
  float4 x1C = *reinterpret_cast<const float4*>(xr1 + 32);
  float4 x1D = *reinterpret_cast<const float4*>(xr1 + 36);

#pragma unroll 1
  for (int it = 0; it < 8; ++it) {
    const size_t p0 = row0 + (size_t)it * 32;
    bf16x8 a0f0, a0f1, a1f0, a1f1;
    {
      uint4 t0 = {pk2(x0A.x, x0A.y), pk2(x0A.z, x0A.w), pk2(x0B.x, x0B.y), pk2(x0B.z, x0B.w)};
      unsigned d0 = (g == 1) ? 0x00003f80u : pk2(x0C.x, x0C.y);
      uint4 t1 = {d0, pk2(x0C.z, x0C.w), pk2(x0D.x, x0D.y), pk2(x0D.z, x0D.w)};
      __builtin_memcpy(&a0f0, &t0, 16);
      __builtin_memcpy(&a0f1, &t1, 16);
      uint4 t2 = {pk2(x1A.x, x1A.y), pk2(x1A.z, x1A.w), pk2(x1B.x, x1B.y), pk2(x1B.z, x1B.w)};
      unsigned d1 = (g == 1) ? 0x00003f80u : pk2(x1C.x, x1C.y);
      uint4 t3 = {d1, pk2(x1C.z, x1C.w), pk2(x1D.x, x1D.y), pk2(x1D.z, x1D.w)};
      __builtin_memcpy(&a1f0, &t2, 16);
      __builtin_memcpy(&a1f1, &t3, 16);
    }
    if (it < 7) {
      const float* nr0 = bias + (p0 + 32 + r) * 40;
      const float* nr1 = bias + (p0 + 48 + r) * 40;
      x0A = *reinterpret_cast<const float4*>(nr0 + g * 8);
      x0B = *reinterpret_cast<const float4*>(nr0 + g * 8 + 4);
      x0C = *reinterpret_cast<const float4*>(nr0 + 32);
      x0D = *reinterpret_cast<const float4*>(nr0 + 36);
      x1A = *reinterpret_cast<const float4*>(nr1 + g * 8);
      x1B = *reinterpret_cast<const float4*>(nr1 + g * 8 + 4);
      x1C = *reinterpret_cast<const float4*>(nr1 + 32);
      x1D = *reinterpret_cast<const float4*>(nr1 + 36);
    }
    TILE_BODY(a0f0, a0f1, p0);
    TILE_BODY(a1f0, a1f1, p0 + 16);
  }
}

// ---------------- fused QK^T + masked-softmax partials ----------------
// Per block: one 64x64 logits tile for head h; emits per-row (m, sum e, sum e*s)
// partials instead of materializing logits.  parts plane = (h*16 + kb)*1024 + row.
__global__ __launch_bounds__(256) void qk_softmax(
    const float* __restrict__ pq, const float* __restrict__ pk,
    const int* __restrict__ mask, const float* __restrict__ diffs,
    const float* __restrict__ sv, float* __restrict__ mpart,
    float* __restrict__ spart, float* __restrict__ dpart) {
  __shared__ float sQT[64][68];
  __shared__ float sKT[64][68];
  int tid = threadIdx.x;
  int k0 = blockIdx.x * 64, q0 = blockIdx.y * 64, h = blockIdx.z;
  for (int i = tid; i < 1024; i += 256) {
    int r = i >> 4, dq = i & 15;
    float4 a = *reinterpret_cast<const float4*>(pq + (size_t)(q0 + r) * 256 + h * 64 + dq * 4);
    sQT[dq * 4 + 0][r] = a.x;
    sQT[dq * 4 + 1][r] = a.y;
    sQT[dq * 4 + 2][r] = a.z;
    sQT[dq * 4 + 3][r] = a.w;
    float4 b = *reinterpret_cast<const float4*>(pk + (size_t)(k0 + r) * 256 + h * 64 + dq * 4);
    sKT[dq * 4 + 0][r] = b.x;
    sKT[dq * 4 + 1][r] = b.y;
    sKT[dq * 4 + 2][r] = b.z;
    sKT[dq * 4 + 3][r] = b.w;
  }
  __syncthreads();
  int ty = tid >> 4, tx = tid & 15;
  float acc[4][4] = {};
#pragma unroll 4
  for (int d = 0; d < 64; ++d) {
    float4 av = *reinterpret_cast<const float4*>(&sQT[d][ty * 4]);
    float4 bv = *reinterpret_cast<const float4*>(&sKT[d][tx * 4]);
    float a[4] = {av.x, av.y, av.z, av.w};
    float b[4] = {bv.x, bv.y, bv.z, bv.w};
#pragma unroll
    for (int i = 0; i < 4; ++i)
#pragma unroll
      for (int j = 0; j < 4; ++j) acc[i][j] = fmaf(a[i], b[j], acc[i][j]);
  }
  float4 s4 = *reinterpret_cast<const float4*>(sv + k0 + tx * 4);
#pragma unroll
  for (int i = 0; i < 4; ++i) {
    int qq = q0 + ty * 4 + i;
    size_t base = (size_t)h * 1048576 + (size_t)qq * 1024 + k0 + tx * 4;
    float4 dv = *reinterpret_cast<const float4*>(diffs + base);
    int4 mv = *reinterpret_cast<const int4*>(mask + (size_t)qq * 1024 + k0 + tx * 4);
    float l0 = mv.x ? fmaf(acc[i][0], 0.125f, dv.x) : NEGV;
    float l1 = mv.y ? fmaf(acc[i][1], 0.125f, dv.y) : NEGV;
    float l2 = mv.z ? fmaf(acc[i][2], 0.125f, dv.z) : NEGV;
    float l3 = mv.w ? fmaf(acc[i][3], 0.125f, dv.w) : NEGV;
    float tm = fmaxf(fmaxf(l0, l1), fmaxf(l2, l3));
    tm = fmaxf(tm, __shfl_xor(tm, 1));
    tm = fmaxf(tm, __shfl_xor(tm, 2));
    tm = fmaxf(tm, __shfl_xor(tm, 4));
    tm = fmaxf(tm, __shfl_xor(tm, 8));
    float e0 = mv.x ? __expf(l0 - tm) : 0.0f;
    float e1 = mv.y ? __expf(l1 - tm) : 0.0f;
    float e2 = mv.z ? __expf(l2 - tm) : 0.0f;
    float e3 = mv.w ? __expf(l3 - tm) : 0.0f;
    float ps = e0 + e1 + e2 + e3;
    float pd = e0 * s4.x + e1 * s4.y + e2 * s4.z + e3 * s4.w;
    ps += __shfl_xor(ps, 1); pd += __shfl_xor(pd, 1);
    ps += __shfl_xor(ps, 2); pd += __shfl_xor(pd, 2);
    ps += __shfl_xor(ps, 4); pd += __shfl_xor(pd, 4);
    ps += __shfl_xor(ps, 8); pd += __shfl_xor(pd, 8);
    if (tx == 0) {
      int plane = (h * 16 + blockIdx.x) * 1024 + qq;
      mpart[plane] = tm;
      spart[plane] = ps;
      dpart[plane] = pd;
    }
  }
}

// ---------------- merge per-tile softmax partials -> vals_mean ----------------
__global__ void vm_reduce(const float* __restrict__ mpart,
                          const float* __restrict__ spart,
                          const float* __restrict__ dpart,
                          float* __restrict__ vm) {
  int q = blockIdx.x * 256 + threadIdx.x;
  float accum = 0.0f;
#pragma unroll
  for (int h = 0; h < 4; ++h) {
    float M = -3e38f;
#pragma unroll
    for (int kb = 0; kb < 16; ++kb)
      M = fmaxf(M, mpart[(h * 16 + kb) * 1024 + q]);
    float s = 0.0f, d = 0.0f;
#pragma unroll
    for (int kb = 0; kb < 16; ++kb) {
      int p = (h * 16 + kb) * 1024 + q;
      float sc = __expf(mpart[p] - M);
      s = fmaf(spart[p], sc, s);
      d = fmaf(dpart[p], sc, d);
    }
    accum += d / s;
  }
  vm[q] = accum * (1.0f / 1024.0f);
}

extern "C" void kernel_launch(void* const* d_in, const int* in_sizes, int n_in,
                              void* d_out, int out_size, void* d_ws, size_t ws_size,
                              hipStream_t stream) {
  const float* q     = (const float*)d_in[0];
  const float* k     = (const float*)d_in[1];
  const float* v     = (const float*)d_in[2];
  const float* bias  = (const float*)d_in[3];
  const int*   mask  = (const int*)d_in[4];
  const float* Wq    = (const float*)d_in[5];
  const float* bq    = (const float*)d_in[6];
  const float* Wk    = (const float*)d_in[7];
  const float* bk    = (const float*)d_in[8];
  const float* Wbias = (const float*)d_in[9];
  const float* bbias = (const float*)d_in[10];
  const float* Wqo   = (const float*)d_in[11];
  const float* bqo   = (const float*)d_in[12];
  const float* Wko   = (const float*)d_in[13];
  const float* bko   = (const float*)d_in[14];
  const float* g_q   = (const float*)d_in[15];
  const float* be_q  = (const float*)d_in[16];
  const float* g_k   = (const float*)d_in[17];
  const float* be_k  = (const float*)d_in[18];
  const float* Wbo   = (const float*)d_in[19];
  const float* bbo   = (const float*)d_in[20];

  float* out = (float*)d_out;
  float* ws  = (float*)d_ws;
  float* projq = ws;                 // 1024x256
  float* projk = ws + 262144;        // 1024x256
  float* qo    = ws + 524288;        // 1024x256
  float* ko    = ws + 786432;        // 1024x256
  float* diffs = ws + 1048576;       // 4 x 1024 x 1024
  float* svec  = ws + 5242880;       // 1024
  float* Mmat  = ws + 5243904;       // 41 x 40 composite
  float* mpart = ws + 5246976;       // 64 x 1024
  float* spart = ws + 5312512;       // 64 x 1024
  float* dpart = ws + 5378048;       // 64 x 1024

  float* q_out    = out;             // 1024x256
  float* k_out    = out + 262144;    // 1024x256
  float* vmean    = out + 524288;    // 1024
  float* bias_out = out + 525312;    // 1024x1024x40

  prep_kernel<<<1065, 64, 0, stream>>>(v, svec, Wbias, bbias, Wbo, Mmat);
  gemm_pair<<<dim3(4, 16, 2), 256, 0, stream>>>(q, Wq, bq, projq,
                                                k, Wk, bk, projk, 0);
  bias_mfma<<<1024, 256, 0, stream>>>(bias, Wbias, bbias, Mmat, bbo, diffs, bias_out);
  gemm_pair<<<dim3(4, 16, 2), 256, 0, stream>>>(projq, Wqo, bqo, qo,
                                                projk, Wko, bko, ko, 1);
  ln_pair<<<dim3(1024, 2), 256, 0, stream>>>(q, qo, g_q, be_q, q_out,
                                             k, ko, g_k, be_k, k_out);
  qk_softmax<<<dim3(16, 16, 4), 256, 0, stream>>>(projq, projk, mask, diffs,
                                                  svec, mpart, spart, dpart);
  vm_reduce<<<4, 256, 0, stream>>>(mpart, spart, dpart, vmean);
}

// Round 12
// 176.754 us; speedup vs baseline: 1.0875x; 1.0875x over previous
//
#include <hip/hip_runtime.h>
#include <hip/hip_bf16.h>
#include <math.h>

#define NEGV -9e15f

typedef short bf16x8 __attribute__((ext_vector_type(8)));
typedef float f32x4 __attribute__((ext_vector_type(4)));

__device__ __forceinline__ unsigned short f2bf(float x) {
  unsigned u = __float_as_uint(x);
  u += 0x7fffu + ((u >> 16) & 1u);
  return (unsigned short)(u >> 16);
}

__device__ __forceinline__ unsigned pk2(float a, float b) {
  __hip_bfloat162 h = __float22bfloat162_rn(make_float2(a, b));
  unsigned u;
  __builtin_memcpy(&u, &h, 4);
  return u;
}

// branchless mish: x * n/(n+2), n = u(u+2), u = e^min(x,30)
__device__ __forceinline__ float mishf(float x) {
  float u = __expf(fminf(x, 30.0f));
  float n = u * (u + 2.0f);
  return x * __fdividef(n, n + 2.0f);
}

// ---------------- prep: svec rows (bid<1024) + M composite rows (bid>=1024) ----------------
__global__ void prep_kernel(const float* __restrict__ v, float* __restrict__ s,
                            const float* __restrict__ Wb, const float* __restrict__ bb,
                            const float* __restrict__ Wo, float* __restrict__ M) {
  int bid = blockIdx.x;
  int lane = threadIdx.x;  // 64
  if (bid < 1024) {
    float4 a = *reinterpret_cast<const float4*>(v + (size_t)bid * 256 + lane * 4);
    float x = a.x + a.y + a.z + a.w;
    for (int off = 32; off; off >>= 1) x += __shfl_down(x, off);
    if (lane == 0) s[bid] = x;
  } else {
    int i = bid - 1024;  // 0..40
    if (lane >= 40) return;
    float acc = 0.0f;
    for (int k = 0; k < 160; ++k) {
      float w = (i < 40) ? Wb[i * 160 + k] : bb[k];
      acc = fmaf(w, Wo[k * 40 + lane], acc);
    }
    M[i * 40 + lane] = acc;
  }
}

// ---------------- paired GEMM: z selects (A,W,bvec,C); C = A @ W(perm) + bvec ----------------
__global__ __launch_bounds__(256) void gemm_pair(
    const float* __restrict__ A0, const float* __restrict__ W0,
    const float* __restrict__ bv0, float* __restrict__ C0,
    const float* __restrict__ A1, const float* __restrict__ W1,
    const float* __restrict__ bv1, float* __restrict__ C1, int perm) {
  const float* A = blockIdx.z ? A1 : A0;
  const float* W = blockIdx.z ? W1 : W0;
  const float* bvec = blockIdx.z ? bv1 : bv0;
  float* C = blockIdx.z ? C1 : C0;
  __shared__ float sAT[16][68];
  __shared__ float sW[16][68];
  int tid = threadIdx.x;
  int c0 = blockIdx.x * 64, r0 = blockIdx.y * 64;
  int ty = tid >> 4, tx = tid & 15;
  float acc[4][4] = {};
  for (int k0 = 0; k0 < 256; k0 += 16) {
    {
      int r = tid >> 2, jq = tid & 3;
      float4 a4 = *reinterpret_cast<const float4*>(A + (size_t)(r0 + r) * 256 + k0 + jq * 4);
      sAT[jq * 4 + 0][r] = a4.x;
      sAT[jq * 4 + 1][r] = a4.y;
      sAT[jq * 4 + 2][r] = a4.z;
      sAT[jq * 4 + 3][r] = a4.w;
    }
    {
      int kk = tid >> 4, cq = tid & 15;
      int gk = k0 + kk;
      int row = perm ? ((gk & 63) * 4 + (gk >> 6)) : gk;
      float4 w4 = *reinterpret_cast<const float4*>(W + (size_t)row * 256 + c0 + cq * 4);
      *reinterpret_cast<float4*>(&sW[kk][cq * 4]) = w4;
    }
    __syncthreads();
#pragma unroll
    for (int kk = 0; kk < 16; ++kk) {
      float4 av = *reinterpret_cast<const float4*>(&sAT[kk][ty * 4]);
      float4 bv = *reinterpret_cast<const float4*>(&sW[kk][tx * 4]);
      float a[4] = {av.x, av.y, av.z, av.w};
      float b[4] = {bv.x, bv.y, bv.z, bv.w};
#pragma unroll
      for (int i = 0; i < 4; ++i)
#pragma unroll
        for (int j = 0; j < 4; ++j) acc[i][j] = fmaf(a[i], b[j], acc[i][j]);
    }
    __syncthreads();
  }
#pragma unroll
  for (int i = 0; i < 4; ++i) {
    int rr = r0 + ty * 4 + i, cc = c0 + tx * 4;
    float4 o;
    o.x = acc[i][0] + bvec[cc + 0];
    o.y = acc[i][1] + bvec[cc + 1];
    o.z = acc[i][2] + bvec[cc + 2];
    o.w = acc[i][3] + bvec[cc + 3];
    *reinterpret_cast<float4*>(C + (size_t)rr * 256 + cc) = o;
  }
}

// ---------------- paired LN: out = LN(x0 + mish(y)) * g + be; y selects q/k ----------------
__global__ __launch_bounds__(256) void ln_pair(
    const float* __restrict__ x0q, const float* __restrict__ yq,
    const float* __restrict__ gq, const float* __restrict__ beq,
    float* __restrict__ outq,
    const float* __restrict__ x0k, const float* __restrict__ yk,
    const float* __restrict__ gk, const float* __restrict__ bek,
    float* __restrict__ outk) {
  const float* x0 = blockIdx.y ? x0k : x0q;
  const float* y  = blockIdx.y ? yk  : yq;
  const float* g  = blockIdx.y ? gk  : gq;
  const float* be = blockIdx.y ? bek : beq;
  float* out      = blockIdx.y ? outk : outq;
  __shared__ float r1[5], r2[5];
  int r = blockIdx.x, t = threadIdx.x;
  int wid = t >> 6, lane = t & 63;
  float x = x0[(size_t)r * 256 + t] + mishf(y[(size_t)r * 256 + t]);
  float a = x, b = x * x;
  for (int off = 32; off; off >>= 1) {
    a += __shfl_down(a, off);
    b += __shfl_down(b, off);
  }
  if (lane == 0) { r1[wid] = a; r2[wid] = b; }
  __syncthreads();
  if (t == 0) {
    r1[4] = r1[0] + r1[1] + r1[2] + r1[3];
    r2[4] = r2[0] + r2[1] + r2[2] + r2[3];
  }
  __syncthreads();
  float m = r1[4] * (1.0f / 256.0f);
  float var = r2[4] * (1.0f / 256.0f) - m * m;
  out[(size_t)r * 256 + t] = (x - m) * rsqrtf(var + 1e-5f) * g[t] + be[t];
}

// ---------------- fused bias path v3: regs-only, 2 tiles/iter (regular stores) ----------------
#define TILE_BODY(XF0, XF1, P0) do {                                                   \
    float hv0, hv1, hv2, hv3;                                                          \
    {                                                                                  \
      f32x4 z = {0.0f, 0.0f, 0.0f, 0.0f};                                              \
      f32x4 q;                                                                         \
      float cs2, cs7;                                                                  \
      q = __builtin_amdgcn_mfma_f32_16x16x32_bf16(wf[0][0], XF0, z, 0, 0, 0);          \
      q = __builtin_amdgcn_mfma_f32_16x16x32_bf16(wf[0][1], XF1, q, 0, 0, 0);          \
      hv0 = q[0]*q[0] + q[1]*q[1] + q[2]*q[2] + q[3]*q[3];                             \
      q = __builtin_amdgcn_mfma_f32_16x16x32_bf16(wf[1][0], XF0, z, 0, 0, 0);          \
      q = __builtin_amdgcn_mfma_f32_16x16x32_bf16(wf[1][1], XF1, q, 0, 0, 0);          \
      hv0 += q[0]*q[0] + q[1]*q[1] + q[2]*q[2] + q[3]*q[3];                            \
      q = __builtin_amdgcn_mfma_f32_16x16x32_bf16(wf[2][0], XF0, z, 0, 0, 0);          \
      q = __builtin_amdgcn_mfma_f32_16x16x32_bf16(wf[2][1], XF1, q, 0, 0, 0);          \
      cs2 = q[0]*q[0] + q[1]*q[1] + q[2]*q[2] + q[3]*q[3];                             \
      q = __builtin_amdgcn_mfma_f32_16x16x32_bf16(wf[3][0], XF0, z, 0, 0, 0);          \
      q = __builtin_amdgcn_mfma_f32_16x16x32_bf16(wf[3][1], XF1, q, 0, 0, 0);          \
      hv1 = q[0]*q[0] + q[1]*q[1] + q[2]*q[2] + q[3]*q[3];                             \
      q = __builtin_amdgcn_mfma_f32_16x16x32_bf16(wf[4][0], XF0, z, 0, 0, 0);          \
      q = __builtin_amdgcn_mfma_f32_16x16x32_bf16(wf[4][1], XF1, q, 0, 0, 0);          \
      hv1 += q[0]*q[0] + q[1]*q[1] + q[2]*q[2] + q[3]*q[3];                            \
      q = __builtin_amdgcn_mfma_f32_16x16x32_bf16(wf[5][0], XF0, z, 0, 0, 0);          \
      q = __builtin_amdgcn_mfma_f32_16x16x32_bf16(wf[5][1], XF1, q, 0, 0, 0);          \
      hv2 = q[0]*q[0] + q[1]*q[1] + q[2]*q[2] + q[3]*q[3];                             \
      q = __builtin_amdgcn_mfma_f32_16x16x32_bf16(wf[6][0], XF0, z, 0, 0, 0);          \
      q = __builtin_amdgcn_mfma_f32_16x16x32_bf16(wf[6][1], XF1, q, 0, 0, 0);          \
      hv2 += q[0]*q[0] + q[1]*q[1] + q[2]*q[2] + q[3]*q[3];                            \
      q = __builtin_amdgcn_mfma_f32_16x16x32_bf16(wf[7][0], XF0, z, 0, 0, 0);          \
      q = __builtin_amdgcn_mfma_f32_16x16x32_bf16(wf[7][1], XF1, q, 0, 0, 0);          \
      cs7 = q[0]*q[0] + q[1]*q[1] + q[2]*q[2] + q[3]*q[3];                             \
      q = __builtin_amdgcn_mfma_f32_16x16x32_bf16(wf[8][0], XF0, z, 0, 0, 0);          \
      q = __builtin_amdgcn_mfma_f32_16x16x32_bf16(wf[8][1], XF1, q, 0, 0, 0);          \
      hv3 = q[0]*q[0] + q[1]*q[1] + q[2]*q[2] + q[3]*q[3];                             \
      q = __builtin_amdgcn_mfma_f32_16x16x32_bf16(wf[9][0], XF0, z, 0, 0, 0);          \
      q = __builtin_amdgcn_mfma_f32_16x16x32_bf16(wf[9][1], XF1, q, 0, 0, 0);          \
      hv3 += q[0]*q[0] + q[1]*q[1] + q[2]*q[2] + q[3]*q[3];                            \
      float csa = (g < 2) ? cs2 : 0.0f;                                                \
      float csb = (g < 2) ? 0.0f : cs2;                                                \
      float csc = (g < 2) ? cs7 : 0.0f;                                                \
      float csd = (g < 2) ? 0.0f : cs7;                                                \
      hv0 += csa; hv1 += csb; hv2 += csc; hv3 += csd;                                  \
    }                                                                                  \
    hv0 += __shfl_xor(hv0, 16); hv0 += __shfl_xor(hv0, 32);                            \
    hv1 += __shfl_xor(hv1, 16); hv1 += __shfl_xor(hv1, 32);                            \
    hv2 += __shfl_xor(hv2, 16); hv2 += __shfl_xor(hv2, 32);                            \
    hv3 += __shfl_xor(hv3, 16); hv3 += __shfl_xor(hv3, 32);                            \
    float ss = (g == 0) ? hv0 : (g == 1) ? hv1 : (g == 2) ? hv2 : hv3;                 \
    diffs[(size_t)g * (1024 * 1024) + (P0) + r] = sqrtf(ss);                           \
    f32x4 o0 = bo40, o1 = bo41, o2 = bo42;                                             \
    o0 = __builtin_amdgcn_mfma_f32_16x16x32_bf16(mf[0][0], XF0, o0, 0, 0, 0);          \
    o1 = __builtin_amdgcn_mfma_f32_16x16x32_bf16(mf[1][0], XF0, o1, 0, 0, 0);          \
    o2 = __builtin_amdgcn_mfma_f32_16x16x32_bf16(mf[2][0], XF0, o2, 0, 0, 0);          \
    o0 = __builtin_amdgcn_mfma_f32_16x16x32_bf16(mf[0][1], XF1, o0, 0, 0, 0);          \
    o1 = __builtin_amdgcn_mfma_f32_16x16x32_bf16(mf[1][1], XF1, o1, 0, 0, 0);          \
    o2 = __builtin_amdgcn_mfma_f32_16x16x32_bf16(mf[2][1], XF1, o2, 0, 0, 0);          \
    float* bp = bout + (size_t)((P0) + r) * 40;                                        \
    float4 st;                                                                         \
    st.x = mishf(o0[0]); st.y = mishf(o0[1]);                                          \
    st.z = mishf(o0[2]); st.w = mishf(o0[3]);                                          \
    *reinterpret_cast<float4*>(bp + 4 * g) = st;                                       \
    st.x = mishf(o1[0]); st.y = mishf(o1[1]);                                          \
    st.z = mishf(o1[2]); st.w = mishf(o1[3]);                                          \
    *reinterpret_cast<float4*>(bp + 16 + 4 * g) = st;                                  \
    if (g < 2) {                                                                       \
      st.x = mishf(o2[0]); st.y = mishf(o2[1]);                                        \
      st.z = mishf(o2[2]); st.w = mishf(o2[3]);                                        \
      *reinterpret_cast<float4*>(bp + 32 + 4 * g) = st;                                \
    }                                                                                  \
  } while (0)

__global__ __launch_bounds__(256, 2) void bias_mfma(
    const float* __restrict__ bias, const float* __restrict__ Wb,
    const float* __restrict__ bb, const float* __restrict__ Mmat,
    const float* __restrict__ bo, float* __restrict__ diffs,
    float* __restrict__ bout) {
  int tid = threadIdx.x;
  int wv = tid >> 6, lane = tid & 63;
  int r = lane & 15, g = lane >> 4;

  // Wb' fragments (A-operand): wf[n0][ks]; k=40 slot carries bb (bias fold)
  bf16x8 wf[10][2];
#pragma unroll
  for (int n0 = 0; n0 < 10; ++n0)
#pragma unroll
    for (int ks = 0; ks < 2; ++ks)
#pragma unroll
      for (int jj = 0; jj < 8; ++jj) {
        int k = ks * 32 + g * 8 + jj;
        int c = n0 * 16 + r;
        float w = (k < 40) ? Wb[k * 160 + c] : ((k == 40) ? bb[c] : 0.0f);
        wf[n0][ks][jj] = (short)f2bf(w);
      }
  // M^T fragments (A-operand): mf[n][ks]
  bf16x8 mf[3][2];
#pragma unroll
  for (int n = 0; n < 3; ++n)
#pragma unroll
    for (int ks = 0; ks < 2; ++ks)
#pragma unroll
      for (int jj = 0; jj < 8; ++jj) {
        int k = ks * 32 + g * 8 + jj;
        int c = n * 16 + r;
        float w = (k <= 40 && c < 40) ? Mmat[k * 40 + c] : 0.0f;
        mf[n][ks][jj] = (short)f2bf(w);
      }
  // bo as per-lane f32x4: cols 16n + 4g .. +3
  f32x4 bo40, bo41, bo42;
  {
    float4 t0 = *reinterpret_cast<const float4*>(bo + 4 * g);
    float4 t1 = *reinterpret_cast<const float4*>(bo + 16 + 4 * g);
    bo40[0] = t0.x; bo40[1] = t0.y; bo40[2] = t0.z; bo40[3] = t0.w;
    bo41[0] = t1.x; bo41[1] = t1.y; bo41[2] = t1.z; bo41[3] = t1.w;
    if (g < 2) {
      float4 t2 = *reinterpret_cast<const float4*>(bo + 32 + 4 * g);
      bo42[0] = t2.x; bo42[1] = t2.y; bo42[2] = t2.z; bo42[3] = t2.w;
    } else {
      bo42[0] = 0.0f; bo42[1] = 0.0f; bo42[2] = 0.0f; bo42[3] = 0.0f;
    }
  }

  size_t row0 = ((size_t)blockIdx.x * 4 + wv) * 256;  // 8 iters x 2 tiles x 16 rows

  // prefetch tiles 0,1
  const float* xr0 = bias + (row0 + r) * 40;
  const float* xr1 = bias + (row0 + 16 + r) * 40;
  float4 x0A = *reinterpret_cast<const float4*>(xr0 + g * 8);
  float4 x0B = *reinterpret_cast<const float4*>(xr0 + g * 8 + 4);
  float4 x0C = *reinterpret_cast<const float4*>(xr0 + 32);
  float4 x0D = *reinterpret_cast<const float4*>(xr0 + 36);
  float4 x1A = *reinterpret_cast<const float4*>(xr1 + g * 8);
  float4 x1B = *reinterpret_cast<const float4*>(xr1 + g * 8 + 4);
  float4 x1C = *reinterpret_cast<const float4*>(xr1 + 32);
  float4 x1D = *reinterpret_cast<const float4*>(xr1 + 36);

#pragma unroll 1
  for (int it = 0; it < 8; ++it) {
    const size_t p0 = row0 + (size_t)it * 32;
    bf16x8 a0f0, a0f1, a1f0, a1f1;
    {
      uint4 t0 = {pk2(x0A.x, x0A.y), pk2(x0A.z, x0A.w), pk2(x0B.x, x0B.y), pk2(x0B.z, x0B.w)};
      unsigned d0 = (g == 1) ? 0x00003f80u : pk2(x0C.x, x0C.y);
      uint4 t1 = {d0, pk2(x0C.z, x0C.w), pk2(x0D.x, x0D.y), pk2(x0D.z, x0D.w)};
      __builtin_memcpy(&a0f0, &t0, 16);
      __builtin_memcpy(&a0f1, &t1, 16);
      uint4 t2 = {pk2(x1A.x, x1A.y), pk2(x1A.z, x1A.w), pk2(x1B.x, x1B.y), pk2(x1B.z, x1B.w)};
      unsigned d1 = (g == 1) ? 0x00003f80u : pk2(x1C.x, x1C.y);
      uint4 t3 = {d1, pk2(x1C.z, x1C.w), pk2(x1D.x, x1D.y), pk2(x1D.z, x1D.w)};
      __builtin_memcpy(&a1f0, &t2, 16);
      __builtin_memcpy(&a1f1, &t3, 16);
    }
    if (it < 7) {
      const float* nr0 = bias + (p0 + 32 + r) * 40;
      const float* nr1 = bias + (p0 + 48 + r) * 40;
      x0A = *reinterpret_cast<const float4*>(nr0 + g * 8);
      x0B = *reinterpret_cast<const float4*>(nr0 + g * 8 + 4);
      x0C = *reinterpret_cast<const float4*>(nr0 + 32);
      x0D = *reinterpret_cast<const float4*>(nr0 + 36);
      x1A = *reinterpret_cast<const float4*>(nr1 + g * 8);
      x1B = *reinterpret_cast<const float4*>(nr1 + g * 8 + 4);
      x1C = *reinterpret_cast<const float4*>(nr1 + 32);
      x1D = *reinterpret_cast<const float4*>(nr1 + 36);
    }
    TILE_BODY(a0f0, a0f1, p0);
    TILE_BODY(a1f0, a1f1, p0 + 16);
  }
}

// ---------------- fused QK^T + masked-softmax partials ----------------
// Per block: one 64x64 logits tile for head h; emits per-row (m, sum e, sum e*s)
// partials instead of materializing logits.  parts plane = (h*16 + kb)*1024 + row.
__global__ __launch_bounds__(256) void qk_softmax(
    const float* __restrict__ pq, const float* __restrict__ pk,
    const int* __restrict__ mask, const float* __restrict__ diffs,
    const float* __restrict__ sv, float* __restrict__ mpart,
    float* __restrict__ spart, float* __restrict__ dpart) {
  __shared__ float sQT[64][68];
  __shared__ float sKT[64][68];
  int tid = threadIdx.x;
  int k0 = blockIdx.x * 64, q0 = blockIdx.y * 64, h = blockIdx.z;
  for (int i = tid; i < 1024; i += 256) {
    int r = i >> 4, dq = i & 15;
    float4 a = *reinterpret_cast<const float4*>(pq + (size_t)(q0 + r) * 256 + h * 64 + dq * 4);
    sQT[dq * 4 + 0][r] = a.x;
    sQT[dq * 4 + 1][r] = a.y;
    sQT[dq * 4 + 2][r] = a.z;
    sQT[dq * 4 + 3][r] = a.w;
    float4 b = *reinterpret_cast<const float4*>(pk + (size_t)(k0 + r) * 256 + h * 64 + dq * 4);
    sKT[dq * 4 + 0][r] = b.x;
    sKT[dq * 4 + 1][r] = b.y;
    sKT[dq * 4 + 2][r] = b.z;
    sKT[dq * 4 + 3][r] = b.w;
  }
  __syncthreads();
  int ty = tid >> 4, tx = tid & 15;
  float acc[4][4] = {};
#pragma unroll 4
  for (int d = 0; d < 64; ++d) {
    float4 av = *reinterpret_cast<const float4*>(&sQT[d][ty * 4]);
    float4 bv = *reinterpret_cast<const float4*>(&sKT[d][tx * 4]);
    float a[4] = {av.x, av.y, av.z, av.w};
    float b[4] = {bv.x, bv.y, bv.z, bv.w};
#pragma unroll
    for (int i = 0; i < 4; ++i)
#pragma unroll
      for (int j = 0; j < 4; ++j) acc[i][j] = fmaf(a[i], b[j], acc[i][j]);
  }
  float4 s4 = *reinterpret_cast<const float4*>(sv + k0 + tx * 4);
#pragma unroll
  for (int i = 0; i < 4; ++i) {
    int qq = q0 + ty * 4 + i;
    size_t base = (size_t)h * 1048576 + (size_t)qq * 1024 + k0 + tx * 4;
    float4 dv = *reinterpret_cast<const float4*>(diffs + base);
    int4 mv = *reinterpret_cast<const int4*>(mask + (size_t)qq * 1024 + k0 + tx * 4);
    float l0 = mv.x ? fmaf(acc[i][0], 0.125f, dv.x) : NEGV;
    float l1 = mv.y ? fmaf(acc[i][1], 0.125f, dv.y) : NEGV;
    float l2 = mv.z ? fmaf(acc[i][2], 0.125f, dv.z) : NEGV;
    float l3 = mv.w ? fmaf(acc[i][3], 0.125f, dv.w) : NEGV;
    float tm = fmaxf(fmaxf(l0, l1), fmaxf(l2, l3));
    tm = fmaxf(tm, __shfl_xor(tm, 1));
    tm = fmaxf(tm, __shfl_xor(tm, 2));
    tm = fmaxf(tm, __shfl_xor(tm, 4));
    tm = fmaxf(tm, __shfl_xor(tm, 8));
    float e0 = mv.x ? __expf(l0 - tm) : 0.0f;
    float e1 = mv.y ? __expf(l1 - tm) : 0.0f;
    float e2 = mv.z ? __expf(l2 - tm) : 0.0f;
    float e3 = mv.w ? __expf(l3 - tm) : 0.0f;
    float ps = e0 + e1 + e2 + e3;
    float pd = e0 * s4.x + e1 * s4.y + e2 * s4.z + e3 * s4.w;
    ps += __shfl_xor(ps, 1); pd += __shfl_xor(pd, 1);
    ps += __shfl_xor(ps, 2); pd += __shfl_xor(pd, 2);
    ps += __shfl_xor(ps, 4); pd += __shfl_xor(pd, 4);
    ps += __shfl_xor(ps, 8); pd += __shfl_xor(pd, 8);
    if (tx == 0) {
      int plane = (h * 16 + blockIdx.x) * 1024 + qq;
      mpart[plane] = tm;
      spart[plane] = ps;
      dpart[plane] = pd;
    }
  }
}

// ---------------- merge per-tile softmax partials -> vals_mean ----------------
__global__ void vm_reduce(const float* __restrict__ mpart,
                          const float* __restrict__ spart,
                          const float* __restrict__ dpart,
                          float* __restrict__ vm) {
  int q = blockIdx.x * 256 + threadIdx.x;
  float accum = 0.0f;
#pragma unroll
  for (int h = 0; h < 4; ++h) {
    float M = -3e38f;
#pragma unroll
    for (int kb = 0; kb < 16; ++kb)
      M = fmaxf(M, mpart[(h * 16 + kb) * 1024 + q]);
    float s = 0.0f, d = 0.0f;
#pragma unroll
    for (int kb = 0; kb < 16; ++kb) {
      int p = (h * 16 + kb) * 1024 + q;
      float sc = __expf(mpart[p] - M);
      s = fmaf(spart[p], sc, s);
      d = fmaf(dpart[p], sc, d);
    }
    accum += d / s;
  }
  vm[q] = accum * (1.0f / 1024.0f);
}

extern "C" void kernel_launch(void* const* d_in, const int* in_sizes, int n_in,
                              void* d_out, int out_size, void* d_ws, size_t ws_size,
                              hipStream_t stream) {
  const float* q     = (const float*)d_in[0];
  const float* k     = (const float*)d_in[1];
  const float* v     = (const float*)d_in[2];
  const float* bias  = (const float*)d_in[3];
  const int*   mask  = (const int*)d_in[4];
  const float* Wq    = (const float*)d_in[5];
  const float* bq    = (const float*)d_in[6];
  const float* Wk    = (const float*)d_in[7];
  const float* bk    = (const float*)d_in[8];
  const float* Wbias = (const float*)d_in[9];
  const float* bbias = (const float*)d_in[10];
  const float* Wqo   = (const float*)d_in[11];
  const float* bqo   = (const float*)d_in[12];
  const float* Wko   = (const float*)d_in[13];
  const float* bko   = (const float*)d_in[14];
  const float* g_q   = (const float*)d_in[15];
  const float* be_q  = (const float*)d_in[16];
  const float* g_k   = (const float*)d_in[17];
  const float* be_k  = (const float*)d_in[18];
  const float* Wbo   = (const float*)d_in[19];
  const float* bbo   = (const float*)d_in[20];

  float* out = (float*)d_out;
  float* ws  = (float*)d_ws;
  float* projq = ws;                 // 1024x256
  float* projk = ws + 262144;        // 1024x256
  float* qo    = ws + 524288;        // 1024x256
  float* ko    = ws + 786432;        // 1024x256
  float* diffs = ws + 1048576;       // 4 x 1024 x 1024
  float* svec  = ws + 5242880;       // 1024
  float* Mmat  = ws + 5243904;       // 41 x 40 composite
  float* mpart = ws + 5246976;       // 64 x 1024
  float* spart = ws + 5312512;       // 64 x 1024
  float* dpart = ws + 5378048;       // 64 x 1024

  float* q_out    = out;             // 1024x256
  float* k_out    = out + 262144;    // 1024x256
  float* vmean    = out + 524288;    // 1024
  float* bias_out = out + 525312;    // 1024x1024x40

  prep_kernel<<<1065, 64, 0, stream>>>(v, svec, Wbias, bbias, Wbo, Mmat);
  gemm_pair<<<dim3(4, 16, 2), 256, 0, stream>>>(q, Wq, bq, projq,
                                                k, Wk, bk, projk, 0);
  bias_mfma<<<1024, 256, 0, stream>>>(bias, Wbias, bbias, Mmat, bbo, diffs, bias_out);
  gemm_pair<<<dim3(4, 16, 2), 256, 0, stream>>>(projq, Wqo, bqo, qo,
                                                projk, Wko, bko, ko, 1);
  ln_pair<<<dim3(1024, 2), 256, 0, stream>>>(q, qo, g_q, be_q, q_out,
                                             k, ko, g_k, be_k, k_out);
  qk_softmax<<<dim3(16, 16, 4), 256, 0, stream>>>(projq, projk, mask, diffs,
                                                  svec, mpart, spart, dpart);
  vm_reduce<<<4, 256, 0, stream>>>(mpart, spart, dpart, vmean);
}

// Round 13
// 159.919 us; speedup vs baseline: 1.2020x; 1.1053x over previous
//
#include <hip/hip_runtime.h>
#include <hip/hip_bf16.h>
#include <math.h>

#define NEGV -9e15f

typedef short bf16x8 __attribute__((ext_vector_type(8)));
typedef float f32x4 __attribute__((ext_vector_type(4)));

__device__ __forceinline__ unsigned short f2bf(float x) {
  unsigned u = __float_as_uint(x);
  u += 0x7fffu + ((u >> 16) & 1u);
  return (unsigned short)(u >> 16);
}

__device__ __forceinline__ unsigned pk2(float a, float b) {
  __hip_bfloat162 h = __float22bfloat162_rn(make_float2(a, b));
  unsigned u;
  __builtin_memcpy(&u, &h, 4);
  return u;
}

// branchless mish: x * n/(n+2), n = u(u+2), u = e^min(x,30)
__device__ __forceinline__ float mishf(float x) {
  float u = __expf(fminf(x, 30.0f));
  float n = u * (u + 2.0f);
  return x * __fdividef(n, n + 2.0f);
}

#define KEEP4(v) asm volatile("" : "+v"((v).x), "+v"((v).y), "+v"((v).z), "+v"((v).w))

// ---------------- prep: svec rows (bid<1024) + M composite rows (bid>=1024) ----------------
__global__ void prep_kernel(const float* __restrict__ v, float* __restrict__ s,
                            const float* __restrict__ Wb, const float* __restrict__ bb,
                            const float* __restrict__ Wo, float* __restrict__ M) {
  int bid = blockIdx.x;
  int lane = threadIdx.x;  // 64
  if (bid < 1024) {
    float4 a = *reinterpret_cast<const float4*>(v + (size_t)bid * 256 + lane * 4);
    float x = a.x + a.y + a.z + a.w;
    for (int off = 32; off; off >>= 1) x += __shfl_down(x, off);
    if (lane == 0) s[bid] = x;
  } else {
    int i = bid - 1024;  // 0..40
    if (lane >= 40) return;
    float acc = 0.0f;
    for (int k = 0; k < 160; ++k) {
      float w = (i < 40) ? Wb[i * 160 + k] : bb[k];
      acc = fmaf(w, Wo[k * 40 + lane], acc);
    }
    M[i * 40 + lane] = acc;
  }
}

// ---------------- paired GEMM: z selects (A,W,bvec,C); C = A @ W(perm) + bvec ----------------
__global__ __launch_bounds__(256) void gemm_pair(
    const float* __restrict__ A0, const float* __restrict__ W0,
    const float* __restrict__ bv0, float* __restrict__ C0,
    const float* __restrict__ A1, const float* __restrict__ W1,
    const float* __restrict__ bv1, float* __restrict__ C1, int perm) {
  const float* A = blockIdx.z ? A1 : A0;
  const float* W = blockIdx.z ? W1 : W0;
  const float* bvec = blockIdx.z ? bv1 : bv0;
  float* C = blockIdx.z ? C1 : C0;
  __shared__ float sAT[16][68];
  __shared__ float sW[16][68];
  int tid = threadIdx.x;
  int c0 = blockIdx.x * 64, r0 = blockIdx.y * 64;
  int ty = tid >> 4, tx = tid & 15;
  float acc[4][4] = {};
  for (int k0 = 0; k0 < 256; k0 += 16) {
    {
      int r = tid >> 2, jq = tid & 3;
      float4 a4 = *reinterpret_cast<const float4*>(A + (size_t)(r0 + r) * 256 + k0 + jq * 4);
      sAT[jq * 4 + 0][r] = a4.x;
      sAT[jq * 4 + 1][r] = a4.y;
      sAT[jq * 4 + 2][r] = a4.z;
      sAT[jq * 4 + 3][r] = a4.w;
    }
    {
      int kk = tid >> 4, cq = tid & 15;
      int gk = k0 + kk;
      int row = perm ? ((gk & 63) * 4 + (gk >> 6)) : gk;
      float4 w4 = *reinterpret_cast<const float4*>(W + (size_t)row * 256 + c0 + cq * 4);
      *reinterpret_cast<float4*>(&sW[kk][cq * 4]) = w4;
    }
    __syncthreads();
#pragma unroll
    for (int kk = 0; kk < 16; ++kk) {
      float4 av = *reinterpret_cast<const float4*>(&sAT[kk][ty * 4]);
      float4 bv = *reinterpret_cast<const float4*>(&sW[kk][tx * 4]);
      float a[4] = {av.x, av.y, av.z, av.w};
      float b[4] = {bv.x, bv.y, bv.z, bv.w};
#pragma unroll
      for (int i = 0; i < 4; ++i)
#pragma unroll
        for (int j = 0; j < 4; ++j) acc[i][j] = fmaf(a[i], b[j], acc[i][j]);
    }
    __syncthreads();
  }
#pragma unroll
  for (int i = 0; i < 4; ++i) {
    int rr = r0 + ty * 4 + i, cc = c0 + tx * 4;
    float4 o;
    o.x = acc[i][0] + bvec[cc + 0];
    o.y = acc[i][1] + bvec[cc + 1];
    o.z = acc[i][2] + bvec[cc + 2];
    o.w = acc[i][3] + bvec[cc + 3];
    *reinterpret_cast<float4*>(C + (size_t)rr * 256 + cc) = o;
  }
}

// ---------------- paired LN: out = LN(x0 + mish(y)) * g + be; y selects q/k ----------------
__global__ __launch_bounds__(256) void ln_pair(
    const float* __restrict__ x0q, const float* __restrict__ yq,
    const float* __restrict__ gq, const float* __restrict__ beq,
    float* __restrict__ outq,
    const float* __restrict__ x0k, const float* __restrict__ yk,
    const float* __restrict__ gk, const float* __restrict__ bek,
    float* __restrict__ outk) {
  const float* x0 = blockIdx.y ? x0k : x0q;
  const float* y  = blockIdx.y ? yk  : yq;
  const float* g  = blockIdx.y ? gk  : gq;
  const float* be = blockIdx.y ? bek : beq;
  float* out      = blockIdx.y ? outk : outq;
  __shared__ float r1[5], r2[5];
  int r = blockIdx.x, t = threadIdx.x;
  int wid = t >> 6, lane = t & 63;
  float x = x0[(size_t)r * 256 + t] + mishf(y[(size_t)r * 256 + t]);
  float a = x, b = x * x;
  for (int off = 32; off; off >>= 1) {
    a += __shfl_down(a, off);
    b += __shfl_down(b, off);
  }
  if (lane == 0) { r1[wid] = a; r2[wid] = b; }
  __syncthreads();
  if (t == 0) {
    r1[4] = r1[0] + r1[1] + r1[2] + r1[3];
    r2[4] = r2[0] + r2[1] + r2[2] + r2[3];
  }
  __syncthreads();
  float m = r1[4] * (1.0f / 256.0f);
  float var = r2[4] * (1.0f / 256.0f) - m * m;
  out[(size_t)r * 256 + t] = (x - m) * rsqrtf(var + 1e-5f) * g[t] + be[t];
}

// ---------------- fused bias path v4: weights in LDS, 4 blocks/CU, pinned prefetch ----------------
// G1 = mfma(Wb'-frag, X-frag) -> norms from accumulators; bout = mish(X@M + bo) via
// composite M (6 MFMA). Weight fragment tables live in LDS (26.6 KB/block -> 4 blocks/CU);
// X prefetch is pinned in VGPRs with asm keep-alives so the allocator cannot remat the
// loads under the launch_bounds(256,4) register cap (round-8 failure mode).
__global__ __launch_bounds__(256, 4) void bias_mfma(
    const float* __restrict__ bias, const float* __restrict__ Wb,
    const float* __restrict__ bb, const float* __restrict__ Mmat,
    const float* __restrict__ bo, float* __restrict__ diffs,
    float* __restrict__ bout) {
  __shared__ unsigned short wfL[20 * 64 * 8];  // [n0*2+ks][lane][jj]  20.5 KB
  __shared__ unsigned short mfL[6 * 64 * 8];   // [n*2+ks][lane][jj]    6 KB
  int tid = threadIdx.x;
  int wv = tid >> 6, lane = tid & 63;
  int r = lane & 15, g = lane >> 4;

  // build Wb' fragment table (k=40 slot carries bb)
  for (int idx = tid; idx < 20 * 64; idx += 256) {
    int grp = idx >> 6, lid = idx & 63;
    int n0 = grp >> 1, ks = grp & 1;
    int rr = lid & 15, gg = lid >> 4;
    int c = n0 * 16 + rr;
    unsigned short tmp[8];
#pragma unroll
    for (int jj = 0; jj < 8; ++jj) {
      int k = ks * 32 + gg * 8 + jj;
      float w = (k < 40) ? Wb[k * 160 + c] : ((k == 40) ? bb[c] : 0.0f);
      tmp[jj] = f2bf(w);
    }
    *reinterpret_cast<uint4*>(&wfL[idx * 8]) = *reinterpret_cast<const uint4*>(tmp);
  }
  // build M^T fragment table
  for (int idx = tid; idx < 6 * 64; idx += 256) {
    int grp = idx >> 6, lid = idx & 63;
    int n = grp >> 1, ks = grp & 1;
    int rr = lid & 15, gg = lid >> 4;
    int c = n * 16 + rr;
    unsigned short tmp[8];
#pragma unroll
    for (int jj = 0; jj < 8; ++jj) {
      int k = ks * 32 + gg * 8 + jj;
      float w = (k <= 40 && c < 40) ? Mmat[k * 40 + c] : 0.0f;
      tmp[jj] = f2bf(w);
    }
    *reinterpret_cast<uint4*>(&mfL[idx * 8]) = *reinterpret_cast<const uint4*>(tmp);
  }
  // bo as per-lane f32x4: cols 16n + 4g .. +3
  f32x4 bo40, bo41, bo42;
  {
    float4 t0 = *reinterpret_cast<const float4*>(bo + 4 * g);
    float4 t1 = *reinterpret_cast<const float4*>(bo + 16 + 4 * g);
    bo40[0] = t0.x; bo40[1] = t0.y; bo40[2] = t0.z; bo40[3] = t0.w;
    bo41[0] = t1.x; bo41[1] = t1.y; bo41[2] = t1.z; bo41[3] = t1.w;
    if (g < 2) {
      float4 t2 = *reinterpret_cast<const float4*>(bo + 32 + 4 * g);
      bo42[0] = t2.x; bo42[1] = t2.y; bo42[2] = t2.z; bo42[3] = t2.w;
    } else {
      bo42[0] = 0.0f; bo42[1] = 0.0f; bo42[2] = 0.0f; bo42[3] = 0.0f;
    }
  }
  __syncthreads();

  size_t row0 = ((size_t)blockIdx.x * 4 + wv) * 256;  // 16 tiles x 16 rows

  // prefetch tile 0 (pinned)
  const float* xr = bias + (row0 + r) * 40;
  float4 xA = *reinterpret_cast<const float4*>(xr + g * 8);
  float4 xB = *reinterpret_cast<const float4*>(xr + g * 8 + 4);
  float4 xC = *reinterpret_cast<const float4*>(xr + 32);
  float4 xD = *reinterpret_cast<const float4*>(xr + 36);
  KEEP4(xA); KEEP4(xB); KEEP4(xC); KEEP4(xD);

#pragma unroll 1
  for (int t = 0; t < 16; ++t) {
    const size_t p0 = row0 + (size_t)t * 16;
    // X fragments; k=40 slot = 1.0 (bias fold); garbage slots hit zero weights
    bf16x8 xf0, xf1;
    {
      uint4 t0 = {pk2(xA.x, xA.y), pk2(xA.z, xA.w), pk2(xB.x, xB.y), pk2(xB.z, xB.w)};
      unsigned d0 = (g == 1) ? 0x00003f80u : pk2(xC.x, xC.y);
      uint4 t1 = {d0, pk2(xC.z, xC.w), pk2(xD.x, xD.y), pk2(xD.z, xD.w)};
      __builtin_memcpy(&xf0, &t0, 16);
      __builtin_memcpy(&xf1, &t1, 16);
    }
    if (t < 15) {
      const float* xr2 = bias + (p0 + 16 + r) * 40;
      xA = *reinterpret_cast<const float4*>(xr2 + g * 8);
      xB = *reinterpret_cast<const float4*>(xr2 + g * 8 + 4);
      xC = *reinterpret_cast<const float4*>(xr2 + 32);
      xD = *reinterpret_cast<const float4*>(xr2 + 36);
      KEEP4(xA); KEEP4(xB); KEEP4(xC); KEEP4(xD);
    }
    // G1: P accumulators -> per-quadrant square sums (bb folded in via k=40)
    float cs[10];
#pragma unroll
    for (int n0 = 0; n0 < 10; ++n0) {
      bf16x8 wa = *reinterpret_cast<const bf16x8*>(&wfL[((n0 * 2 + 0) * 64 + lane) * 8]);
      bf16x8 wb2 = *reinterpret_cast<const bf16x8*>(&wfL[((n0 * 2 + 1) * 64 + lane) * 8]);
      f32x4 q = {0.0f, 0.0f, 0.0f, 0.0f};
      q = __builtin_amdgcn_mfma_f32_16x16x32_bf16(wa, xf0, q, 0, 0, 0);
      q = __builtin_amdgcn_mfma_f32_16x16x32_bf16(wb2, xf1, q, 0, 0, 0);
      cs[n0] = q[0] * q[0] + q[1] * q[1] + q[2] * q[2] + q[3] * q[3];
    }
    float hv0 = cs[0] + cs[1] + ((g < 2) ? cs[2] : 0.0f);
    float hv1 = ((g < 2) ? 0.0f : cs[2]) + cs[3] + cs[4];
    float hv2 = cs[5] + cs[6] + ((g < 2) ? cs[7] : 0.0f);
    float hv3 = ((g < 2) ? 0.0f : cs[7]) + cs[8] + cs[9];
    hv0 += __shfl_xor(hv0, 16); hv0 += __shfl_xor(hv0, 32);
    hv1 += __shfl_xor(hv1, 16); hv1 += __shfl_xor(hv1, 32);
    hv2 += __shfl_xor(hv2, 16); hv2 += __shfl_xor(hv2, 32);
    hv3 += __shfl_xor(hv3, 16); hv3 += __shfl_xor(hv3, 32);
    float ss = (g == 0) ? hv0 : (g == 1) ? hv1 : (g == 2) ? hv2 : hv3;
    diffs[(size_t)g * (1024 * 1024) + p0 + r] = sqrtf(ss);
    // G2': OUT = mish(X @ M + bo); lane (r,g) holds OUT[row r][cols 16n+4g..+3]
    f32x4 o0 = bo40, o1 = bo41, o2 = bo42;
    {
      bf16x8 m00 = *reinterpret_cast<const bf16x8*>(&mfL[((0 * 2 + 0) * 64 + lane) * 8]);
      bf16x8 m01 = *reinterpret_cast<const bf16x8*>(&mfL[((0 * 2 + 1) * 64 + lane) * 8]);
      bf16x8 m10 = *reinterpret_cast<const bf16x8*>(&mfL[((1 * 2 + 0) * 64 + lane) * 8]);
      bf16x8 m11 = *reinterpret_cast<const bf16x8*>(&mfL[((1 * 2 + 1) * 64 + lane) * 8]);
      bf16x8 m20 = *reinterpret_cast<const bf16x8*>(&mfL[((2 * 2 + 0) * 64 + lane) * 8]);
      bf16x8 m21 = *reinterpret_cast<const bf16x8*>(&mfL[((2 * 2 + 1) * 64 + lane) * 8]);
      o0 = __builtin_amdgcn_mfma_f32_16x16x32_bf16(m00, xf0, o0, 0, 0, 0);
      o1 = __builtin_amdgcn_mfma_f32_16x16x32_bf16(m10, xf0, o1, 0, 0, 0);
      o2 = __builtin_amdgcn_mfma_f32_16x16x32_bf16(m20, xf0, o2, 0, 0, 0);
      o0 = __builtin_amdgcn_mfma_f32_16x16x32_bf16(m01, xf1, o0, 0, 0, 0);
      o1 = __builtin_amdgcn_mfma_f32_16x16x32_bf16(m11, xf1, o1, 0, 0, 0);
      o2 = __builtin_amdgcn_mfma_f32_16x16x32_bf16(m21, xf1, o2, 0, 0, 0);
    }
    float* bp = bout + (size_t)(p0 + r) * 40;
    float4 st;
    st.x = mishf(o0[0]); st.y = mishf(o0[1]);
    st.z = mishf(o0[2]); st.w = mishf(o0[3]);
    *reinterpret_cast<float4*>(bp + 4 * g) = st;
    st.x = mishf(o1[0]); st.y = mishf(o1[1]);
    st.z = mishf(o1[2]); st.w = mishf(o1[3]);
    *reinterpret_cast<float4*>(bp + 16 + 4 * g) = st;
    if (g < 2) {
      st.x = mishf(o2[0]); st.y = mishf(o2[1]);
      st.z = mishf(o2[2]); st.w = mishf(o2[3]);
      *reinterpret_cast<float4*>(bp + 32 + 4 * g) = st;
    }
  }
}

// ---------------- fused QK^T + masked-softmax partials ----------------
__global__ __launch_bounds__(256) void qk_softmax(
    const float* __restrict__ pq, const float* __restrict__ pk,
    const int* __restrict__ mask, const float* __restrict__ diffs,
    const float* __restrict__ sv, float* __restrict__ mpart,
    float* __restrict__ spart, float* __restrict__ dpart) {
  __shared__ float sQT[64][68];
  __shared__ float sKT[64][68];
  int tid = threadIdx.x;
  int k0 = blockIdx.x * 64, q0 = blockIdx.y * 64, h = blockIdx.z;
  for (int i = tid; i < 1024; i += 256) {
    int r = i >> 4, dq = i & 15;
    float4 a = *reinterpret_cast<const float4*>(pq + (size_t)(q0 + r) * 256 + h * 64 + dq * 4);
    sQT[dq * 4 + 0][r] = a.x;
    sQT[dq * 4 + 1][r] = a.y;
    sQT[dq * 4 + 2][r] = a.z;
    sQT[dq * 4 + 3][r] = a.w;
    float4 b = *reinterpret_cast<const float4*>(pk + (size_t)(k0 + r) * 256 + h * 64 + dq * 4);
    sKT[dq * 4 + 0][r] = b.x;
    sKT[dq * 4 + 1][r] = b.y;
    sKT[dq * 4 + 2][r] = b.z;
    sKT[dq * 4 + 3][r] = b.w;
  }
  __syncthreads();
  int ty = tid >> 4, tx = tid & 15;
  float acc[4][4] = {};
#pragma unroll 4
  for (int d = 0; d < 64; ++d) {
    float4 av = *reinterpret_cast<const float4*>(&sQT[d][ty * 4]);
    float4 bv = *reinterpret_cast<const float4*>(&sKT[d][tx * 4]);
    float a[4] = {av.x, av.y, av.z, av.w};
    float b[4] = {bv.x, bv.y, bv.z, bv.w};
#pragma unroll
    for (int i = 0; i < 4; ++i)
#pragma unroll
      for (int j = 0; j < 4; ++j) acc[i][j] = fmaf(a[i], b[j], acc[i][j]);
  }
  float4 s4 = *reinterpret_cast<const float4*>(sv + k0 + tx * 4);
#pragma unroll
  for (int i = 0; i < 4; ++i) {
    int qq = q0 + ty * 4 + i;
    size_t base = (size_t)h * 1048576 + (size_t)qq * 1024 + k0 + tx * 4;
    float4 dv = *reinterpret_cast<const float4*>(diffs + base);
    int4 mv = *reinterpret_cast<const int4*>(mask + (size_t)qq * 1024 + k0 + tx * 4);
    float l0 = mv.x ? fmaf(acc[i][0], 0.125f, dv.x) : NEGV;
    float l1 = mv.y ? fmaf(acc[i][1], 0.125f, dv.y) : NEGV;
    float l2 = mv.z ? fmaf(acc[i][2], 0.125f, dv.z) : NEGV;
    float l3 = mv.w ? fmaf(acc[i][3], 0.125f, dv.w) : NEGV;
    float tm = fmaxf(fmaxf(l0, l1), fmaxf(l2, l3));
    tm = fmaxf(tm, __shfl_xor(tm, 1));
    tm = fmaxf(tm, __shfl_xor(tm, 2));
    tm = fmaxf(tm, __shfl_xor(tm, 4));
    tm = fmaxf(tm, __shfl_xor(tm, 8));
    float e0 = mv.x ? __expf(l0 - tm) : 0.0f;
    float e1 = mv.y ? __expf(l1 - tm) : 0.0f;
    float e2 = mv.z ? __expf(l2 - tm) : 0.0f;
    float e3 = mv.w ? __expf(l3 - tm) : 0.0f;
    float ps = e0 + e1 + e2 + e3;
    float pd = e0 * s4.x + e1 * s4.y + e2 * s4.z + e3 * s4.w;
    ps += __shfl_xor(ps, 1); pd += __shfl_xor(pd, 1);
    ps += __shfl_xor(ps, 2); pd += __shfl_xor(pd, 2);
    ps += __shfl_xor(ps, 4); pd += __shfl_xor(pd, 4);
    ps += __shfl_xor(ps, 8); pd += __shfl_xor(pd, 8);
    if (tx == 0) {
      int plane = (h * 16 + blockIdx.x) * 1024 + qq;
      mpart[plane] = tm;
      spart[plane] = ps;
      dpart[plane] = pd;
    }
  }
}

// ---------------- merge per-tile softmax partials -> vals_mean ----------------
__global__ void vm_reduce(const float* __restrict__ mpart,
                          const float* __restrict__ spart,
                          const float* __restrict__ dpart,
                          float* __restrict__ vm) {
  int q = blockIdx.x * 256 + threadIdx.x;
  float accum = 0.0f;
#pragma unroll
  for (int h = 0; h < 4; ++h) {
    float M = -3e38f;
#pragma unroll
    for (int kb = 0; kb < 16; ++kb)
      M = fmaxf(M, mpart[(h * 16 + kb) * 1024 + q]);
    float s = 0.0f, d = 0.0f;
#pragma unroll
    for (int kb = 0; kb < 16; ++kb) {
      int p = (h * 16 + kb) * 1024 + q;
      float sc = __expf(mpart[p] - M);
      s = fmaf(spart[p], sc, s);
      d = fmaf(dpart[p], sc, d);
    }
    accum += d / s;
  }
  vm[q] = accum * (1.0f / 1024.0f);
}

extern "C" void kernel_launch(void* const* d_in, const int* in_sizes, int n_in,
                              void* d_out, int out_size, void* d_ws, size_t ws_size,
                              hipStream_t stream) {
  const float* q     = (const float*)d_in[0];
  const float* k     = (const float*)d_in[1];
  const float* v     = (const float*)d_in[2];
  const float* bias  = (const float*)d_in[3];
  const int*   mask  = (const int*)d_in[4];
  const float* Wq    = (const float*)d_in[5];
  const float* bq    = (const float*)d_in[6];
  const float* Wk    = (const float*)d_in[7];
  const float* bk    = (const float*)d_in[8];
  const float* Wbias = (const float*)d_in[9];
  const float* bbias = (const float*)d_in[10];
  const float* Wqo   = (const float*)d_in[11];
  const float* bqo   = (const float*)d_in[12];
  const float* Wko   = (const float*)d_in[13];
  const float* bko   = (const float*)d_in[14];
  const float* g_q   = (const float*)d_in[15];
  const float* be_q  = (const float*)d_in[16];
  const float* g_k   = (const float*)d_in[17];
  const float* be_k  = (const float*)d_in[18];
  const float* Wbo   = (const float*)d_in[19];
  const float* bbo   = (const float*)d_in[20];

  float* out = (float*)d_out;
  float* ws  = (float*)d_ws;
  float* projq = ws;                 // 1024x256
  float* projk = ws + 262144;        // 1024x256
  float* qo    = ws + 524288;        // 1024x256
  float* ko    = ws + 786432;        // 1024x256
  float* diffs = ws + 1048576;       // 4 x 1024 x 1024
  float* svec  = ws + 5242880;       // 1024
  float* Mmat  = ws + 5243904;       // 41 x 40 composite
  float* mpart = ws + 5246976;       // 64 x 1024
  float* spart = ws + 5312512;       // 64 x 1024
  float* dpart = ws + 5378048;       // 64 x 1024

  float* q_out    = out;             // 1024x256
  float* k_out    = out + 262144;    // 1024x256
  float* vmean    = out + 524288;    // 1024
  float* bias_out = out + 525312;    // 1024x1024x40

  prep_kernel<<<1065, 64, 0, stream>>>(v, svec, Wbias, bbias, Wbo, Mmat);
  gemm_pair<<<dim3(4, 16, 2), 256, 0, stream>>>(q, Wq, bq, projq,
                                                k, Wk, bk, projk, 0);
  bias_mfma<<<1024, 256, 0, stream>>>(bias, Wbias, bbias, Mmat, bbo, diffs, bias_out);
  gemm_pair<<<dim3(4, 16, 2), 256, 0, stream>>>(projq, Wqo, bqo, qo,
                                                projk, Wko, bko, ko, 1);
  ln_pair<<<dim3(1024, 2), 256, 0, stream>>>(q, qo, g_q, be_q, q_out,
                                             k, ko, g_k, be_k, k_out);
  qk_softmax<<<dim3(16, 16, 4), 256, 0, stream>>>(projq, projk, mask, diffs,
                                                  svec, mpart, spart, dpart);
  vm_reduce<<<4, 256, 0, stream>>>(mpart, spart, dpart, vmean);
}

// Round 14
// 141.015 us; speedup vs baseline: 1.3631x; 1.1341x over previous
//
#include <hip/hip_runtime.h>
#include <hip/hip_bf16.h>
#include <math.h>

#define NEGV -9e15f

typedef short bf16x8 __attribute__((ext_vector_type(8)));
typedef float f32x4 __attribute__((ext_vector_type(4)));

__device__ __forceinline__ unsigned short f2bf(float x) {
  unsigned u = __float_as_uint(x);
  u += 0x7fffu + ((u >> 16) & 1u);
  return (unsigned short)(u >> 16);
}

__device__ __forceinline__ unsigned pk2(float a, float b) {
  __hip_bfloat162 h = __float22bfloat162_rn(make_float2(a, b));
  unsigned u;
  __builtin_memcpy(&u, &h, 4);
  return u;
}

// branchless mish: x * n/(n+2), n = u(u+2), u = e^min(x,30)
__device__ __forceinline__ float mishf(float x) {
  float u = __expf(fminf(x, 30.0f));
  float n = u * (u + 2.0f);
  return x * __fdividef(n, n + 2.0f);
}

#define KEEP4(v) asm volatile("" : "+v"((v).x), "+v"((v).y), "+v"((v).z), "+v"((v).w))

// ---------------- prep: svec rows (bid<1024) + M composite rows (bid>=1024) ----------------
__global__ void prep_kernel(const float* __restrict__ v, float* __restrict__ s,
                            const float* __restrict__ Wb, const float* __restrict__ bb,
                            const float* __restrict__ Wo, float* __restrict__ M) {
  int bid = blockIdx.x;
  int lane = threadIdx.x;  // 64
  if (bid < 1024) {
    float4 a = *reinterpret_cast<const float4*>(v + (size_t)bid * 256 + lane * 4);
    float x = a.x + a.y + a.z + a.w;
    for (int off = 32; off; off >>= 1) x += __shfl_down(x, off);
    if (lane == 0) s[bid] = x;
  } else {
    int i = bid - 1024;  // 0..40
    if (lane >= 40) return;
    float acc = 0.0f;
    for (int k = 0; k < 160; ++k) {
      float w = (i < 40) ? Wb[i * 160 + k] : bb[k];
      acc = fmaf(w, Wo[k * 40 + lane], acc);
    }
    M[i * 40 + lane] = acc;
  }
}

// ---------------- paired GEMM via MFMA bf16: C = A @ W(perm) + bvec ----------------
// Mirrors the verified bias G2' fragment recipe: W^T frag table in LDS; lane (r,g)
// computes C[row r][cols 16n+4g..+3]; f32 accumulate; coalesced float4 stores.
__global__ __launch_bounds__(256, 2) void gemm_mfma_pair(
    const float* __restrict__ A0, const float* __restrict__ W0,
    const float* __restrict__ bv0, float* __restrict__ C0,
    const float* __restrict__ A1, const float* __restrict__ W1,
    const float* __restrict__ bv1, float* __restrict__ C1, int perm) {
  const float* A = blockIdx.z ? A1 : A0;
  const float* W = blockIdx.z ? W1 : W0;
  const float* bvec = blockIdx.z ? bv1 : bv0;
  float* C = blockIdx.z ? C1 : C0;
  __shared__ unsigned short wT[4 * 8 * 64 * 8];  // 32 KB: [(n*8+ks)*64+lane][jj]
  int tid = threadIdx.x;
  int wv = tid >> 6, lane = tid & 63;
  int r = lane & 15, g = lane >> 4;
  int c0 = blockIdx.x * 64, r0 = blockIdx.y * 64;

  // build W^T fragment table
  for (int idx = tid; idx < 4 * 8 * 64; idx += 256) {
    int grp = idx >> 6, lid = idx & 63;
    int n = grp >> 3, ks = grp & 7;
    int cc = c0 + n * 16 + (lid & 15);
    int kbase = ks * 32 + (lid >> 4) * 8;
    unsigned short tmp[8];
#pragma unroll
    for (int jj = 0; jj < 8; ++jj) {
      int k = kbase + jj;
      int row = perm ? ((k & 63) * 4 + (k >> 6)) : k;
      tmp[jj] = f2bf(W[row * 256 + cc]);
    }
    *reinterpret_cast<uint4*>(&wT[idx * 8]) = *reinterpret_cast<const uint4*>(tmp);
  }
  // preload my X row chunks (full row, max MLP): row = r0 + wv*16 + r
  const float* xr = A + (size_t)(r0 + wv * 16 + r) * 256 + g * 8;
  float4 xa[8], xb[8];
#pragma unroll
  for (int ks = 0; ks < 8; ++ks) {
    xa[ks] = *reinterpret_cast<const float4*>(xr + ks * 32);
    xb[ks] = *reinterpret_cast<const float4*>(xr + ks * 32 + 4);
  }
  // bias init: acc[n] = bvec[c0 + 16n + 4g .. +3]
  f32x4 acc[4];
#pragma unroll
  for (int n = 0; n < 4; ++n) {
    float4 b4 = *reinterpret_cast<const float4*>(bvec + c0 + n * 16 + 4 * g);
    acc[n][0] = b4.x; acc[n][1] = b4.y; acc[n][2] = b4.z; acc[n][3] = b4.w;
  }
  __syncthreads();
#pragma unroll
  for (int ks = 0; ks < 8; ++ks) {
    bf16x8 xf;
    uint4 t = {pk2(xa[ks].x, xa[ks].y), pk2(xa[ks].z, xa[ks].w),
               pk2(xb[ks].x, xb[ks].y), pk2(xb[ks].z, xb[ks].w)};
    __builtin_memcpy(&xf, &t, 16);
#pragma unroll
    for (int n = 0; n < 4; ++n) {
      bf16x8 wf = *reinterpret_cast<const bf16x8*>(&wT[((n * 8 + ks) * 64 + lane) * 8]);
      acc[n] = __builtin_amdgcn_mfma_f32_16x16x32_bf16(wf, xf, acc[n], 0, 0, 0);
    }
  }
  float* cp = C + (size_t)(r0 + wv * 16 + r) * 256 + c0;
#pragma unroll
  for (int n = 0; n < 4; ++n) {
    float4 o = {acc[n][0], acc[n][1], acc[n][2], acc[n][3]};
    *reinterpret_cast<float4*>(cp + n * 16 + 4 * g) = o;
  }
}

// ---------------- paired LN: out = LN(x0 + mish(y)) * g + be; y selects q/k ----------------
__global__ __launch_bounds__(256) void ln_pair(
    const float* __restrict__ x0q, const float* __restrict__ yq,
    const float* __restrict__ gq, const float* __restrict__ beq,
    float* __restrict__ outq,
    const float* __restrict__ x0k, const float* __restrict__ yk,
    const float* __restrict__ gk, const float* __restrict__ bek,
    float* __restrict__ outk) {
  const float* x0 = blockIdx.y ? x0k : x0q;
  const float* y  = blockIdx.y ? yk  : yq;
  const float* g  = blockIdx.y ? gk  : gq;
  const float* be = blockIdx.y ? bek : beq;
  float* out      = blockIdx.y ? outk : outq;
  __shared__ float r1[5], r2[5];
  int r = blockIdx.x, t = threadIdx.x;
  int wid = t >> 6, lane = t & 63;
  float x = x0[(size_t)r * 256 + t] + mishf(y[(size_t)r * 256 + t]);
  float a = x, b = x * x;
  for (int off = 32; off; off >>= 1) {
    a += __shfl_down(a, off);
    b += __shfl_down(b, off);
  }
  if (lane == 0) { r1[wid] = a; r2[wid] = b; }
  __syncthreads();
  if (t == 0) {
    r1[4] = r1[0] + r1[1] + r1[2] + r1[3];
    r2[4] = r2[0] + r2[1] + r2[2] + r2[3];
  }
  __syncthreads();
  float m = r1[4] * (1.0f / 256.0f);
  float var = r2[4] * (1.0f / 256.0f) - m * m;
  out[(size_t)r * 256 + t] = (x - m) * rsqrtf(var + 1e-5f) * g[t] + be[t];
}

// ---------------- fused bias path v4: weights in LDS, 4 blocks/CU, pinned prefetch ----------------
__global__ __launch_bounds__(256, 4) void bias_mfma(
    const float* __restrict__ bias, const float* __restrict__ Wb,
    const float* __restrict__ bb, const float* __restrict__ Mmat,
    const float* __restrict__ bo, float* __restrict__ diffs,
    float* __restrict__ bout) {
  __shared__ unsigned short wfL[20 * 64 * 8];  // 20.5 KB
  __shared__ unsigned short mfL[6 * 64 * 8];   // 6 KB
  int tid = threadIdx.x;
  int wv = tid >> 6, lane = tid & 63;
  int r = lane & 15, g = lane >> 4;

  for (int idx = tid; idx < 20 * 64; idx += 256) {
    int grp = idx >> 6, lid = idx & 63;
    int n0 = grp >> 1, ks = grp & 1;
    int rr = lid & 15, gg = lid >> 4;
    int c = n0 * 16 + rr;
    unsigned short tmp[8];
#pragma unroll
    for (int jj = 0; jj < 8; ++jj) {
      int k = ks * 32 + gg * 8 + jj;
      float w = (k < 40) ? Wb[k * 160 + c] : ((k == 40) ? bb[c] : 0.0f);
      tmp[jj] = f2bf(w);
    }
    *reinterpret_cast<uint4*>(&wfL[idx * 8]) = *reinterpret_cast<const uint4*>(tmp);
  }
  for (int idx = tid; idx < 6 * 64; idx += 256) {
    int grp = idx >> 6, lid = idx & 63;
    int n = grp >> 1, ks = grp & 1;
    int rr = lid & 15, gg = lid >> 4;
    int c = n * 16 + rr;
    unsigned short tmp[8];
#pragma unroll
    for (int jj = 0; jj < 8; ++jj) {
      int k = ks * 32 + gg * 8 + jj;
      float w = (k <= 40 && c < 40) ? Mmat[k * 40 + c] : 0.0f;
      tmp[jj] = f2bf(w);
    }
    *reinterpret_cast<uint4*>(&mfL[idx * 8]) = *reinterpret_cast<const uint4*>(tmp);
  }
  f32x4 bo40, bo41, bo42;
  {
    float4 t0 = *reinterpret_cast<const float4*>(bo + 4 * g);
    float4 t1 = *reinterpret_cast<const float4*>(bo + 16 + 4 * g);
    bo40[0] = t0.x; bo40[1] = t0.y; bo40[2] = t0.z; bo40[3] = t0.w;
    bo41[0] = t1.x; bo41[1] = t1.y; bo41[2] = t1.z; bo41[3] = t1.w;
    if (g < 2) {
      float4 t2 = *reinterpret_cast<const float4*>(bo + 32 + 4 * g);
      bo42[0] = t2.x; bo42[1] = t2.y; bo42[2] = t2.z; bo42[3] = t2.w;
    } else {
      bo42[0] = 0.0f; bo42[1] = 0.0f; bo42[2] = 0.0f; bo42[3] = 0.0f;
    }
  }
  __syncthreads();

  size_t row0 = ((size_t)blockIdx.x * 4 + wv) * 256;

  const float* xr = bias + (row0 + r) * 40;
  float4 xA = *reinterpret_cast<const float4*>(xr + g * 8);
  float4 xB = *reinterpret_cast<const float4*>(xr + g * 8 + 4);
  float4 xC = *reinterpret_cast<const float4*>(xr + 32);
  float4 xD = *reinterpret_cast<const float4*>(xr + 36);
  KEEP4(xA); KEEP4(xB); KEEP4(xC); KEEP4(xD);

#pragma unroll 1
  for (int t = 0; t < 16; ++t) {
    const size_t p0 = row0 + (size_t)t * 16;
    bf16x8 xf0, xf1;
    {
      uint4 t0 = {pk2(xA.x, xA.y), pk2(xA.z, xA.w), pk2(xB.x, xB.y), pk2(xB.z, xB.w)};
      unsigned d0 = (g == 1) ? 0x00003f80u : pk2(xC.x, xC.y);
      uint4 t1 = {d0, pk2(xC.z, xC.w), pk2(xD.x, xD.y), pk2(xD.z, xD.w)};
      __builtin_memcpy(&xf0, &t0, 16);
      __builtin_memcpy(&xf1, &t1, 16);
    }
    if (t < 15) {
      const float* xr2 = bias + (p0 + 16 + r) * 40;
      xA = *reinterpret_cast<const float4*>(xr2 + g * 8);
      xB = *reinterpret_cast<const float4*>(xr2 + g * 8 + 4);
      xC = *reinterpret_cast<const float4*>(xr2 + 32);
      xD = *reinterpret_cast<const float4*>(xr2 + 36);
      KEEP4(xA); KEEP4(xB); KEEP4(xC); KEEP4(xD);
    }
    float cs[10];
#pragma unroll
    for (int n0 = 0; n0 < 10; ++n0) {
      bf16x8 wa = *reinterpret_cast<const bf16x8*>(&wfL[((n0 * 2 + 0) * 64 + lane) * 8]);
      bf16x8 wb2 = *reinterpret_cast<const bf16x8*>(&wfL[((n0 * 2 + 1) * 64 + lane) * 8]);
      f32x4 q = {0.0f, 0.0f, 0.0f, 0.0f};
      q = __builtin_amdgcn_mfma_f32_16x16x32_bf16(wa, xf0, q, 0, 0, 0);
      q = __builtin_amdgcn_mfma_f32_16x16x32_bf16(wb2, xf1, q, 0, 0, 0);
      cs[n0] = q[0] * q[0] + q[1] * q[1] + q[2] * q[2] + q[3] * q[3];
    }
    float hv0 = cs[0] + cs[1] + ((g < 2) ? cs[2] : 0.0f);
    float hv1 = ((g < 2) ? 0.0f : cs[2]) + cs[3] + cs[4];
    float hv2 = cs[5] + cs[6] + ((g < 2) ? cs[7] : 0.0f);
    float hv3 = ((g < 2) ? 0.0f : cs[7]) + cs[8] + cs[9];
    hv0 += __shfl_xor(hv0, 16); hv0 += __shfl_xor(hv0, 32);
    hv1 += __shfl_xor(hv1, 16); hv1 += __shfl_xor(hv1, 32);
    hv2 += __shfl_xor(hv2, 16); hv2 += __shfl_xor(hv2, 32);
    hv3 += __shfl_xor(hv3, 16); hv3 += __shfl_xor(hv3, 32);
    float ss = (g == 0) ? hv0 : (g == 1) ? hv1 : (g == 2) ? hv2 : hv3;
    diffs[(size_t)g * (1024 * 1024) + p0 + r] = sqrtf(ss);
    f32x4 o0 = bo40, o1 = bo41, o2 = bo42;
    {
      bf16x8 m00 = *reinterpret_cast<const bf16x8*>(&mfL[((0 * 2 + 0) * 64 + lane) * 8]);
      bf16x8 m01 = *reinterpret_cast<const bf16x8*>(&mfL[((0 * 2 + 1) * 64 + lane) * 8]);
      bf16x8 m10 = *reinterpret_cast<const bf16x8*>(&mfL[((1 * 2 + 0) * 64 + lane) * 8]);
      bf16x8 m11 = *reinterpret_cast<const bf16x8*>(&mfL[((1 * 2 + 1) * 64 + lane) * 8]);
      bf16x8 m20 = *reinterpret_cast<const bf16x8*>(&mfL[((2 * 2 + 0) * 64 + lane) * 8]);
      bf16x8 m21 = *reinterpret_cast<const bf16x8*>(&mfL[((2 * 2 + 1) * 64 + lane) * 8]);
      o0 = __builtin_amdgcn_mfma_f32_16x16x32_bf16(m00, xf0, o0, 0, 0, 0);
      o1 = __builtin_amdgcn_mfma_f32_16x16x32_bf16(m10, xf0, o1, 0, 0, 0);
      o2 = __builtin_amdgcn_mfma_f32_16x16x32_bf16(m20, xf0, o2, 0, 0, 0);
      o0 = __builtin_amdgcn_mfma_f32_16x16x32_bf16(m01, xf1, o0, 0, 0, 0);
      o1 = __builtin_amdgcn_mfma_f32_16x16x32_bf16(m11, xf1, o1, 0, 0, 0);
      o2 = __builtin_amdgcn_mfma_f32_16x16x32_bf16(m21, xf1, o2, 0, 0, 0);
    }
    float* bp = bout + (size_t)(p0 + r) * 40;
    float4 st;
    st.x = mishf(o0[0]); st.y = mishf(o0[1]);
    st.z = mishf(o0[2]); st.w = mishf(o0[3]);
    *reinterpret_cast<float4*>(bp + 4 * g) = st;
    st.x = mishf(o1[0]); st.y = mishf(o1[1]);
    st.z = mishf(o1[2]); st.w = mishf(o1[3]);
    *reinterpret_cast<float4*>(bp + 16 + 4 * g) = st;
    if (g < 2) {
      st.x = mishf(o2[0]); st.y = mishf(o2[1]);
      st.z = mishf(o2[2]); st.w = mishf(o2[3]);
      *reinterpret_cast<float4*>(bp + 32 + 4 * g) = st;
    }
  }
}

// ---------------- fused QK^T + masked-softmax partials ----------------
__global__ __launch_bounds__(256) void qk_softmax(
    const float* __restrict__ pq, const float* __restrict__ pk,
    const int* __restrict__ mask, const float* __restrict__ diffs,
    const float* __restrict__ sv, float* __restrict__ mpart,
    float* __restrict__ spart, float* __restrict__ dpart) {
  __shared__ float sQT[64][68];
  __shared__ float sKT[64][68];
  int tid = threadIdx.x;
  int k0 = blockIdx.x * 64, q0 = blockIdx.y * 64, h = blockIdx.z;
  for (int i = tid; i < 1024; i += 256) {
    int r = i >> 4, dq = i & 15;
    float4 a = *reinterpret_cast<const float4*>(pq + (size_t)(q0 + r) * 256 + h * 64 + dq * 4);
    sQT[dq * 4 + 0][r] = a.x;
    sQT[dq * 4 + 1][r] = a.y;
    sQT[dq * 4 + 2][r] = a.z;
    sQT[dq * 4 + 3][r] = a.w;
    float4 b = *reinterpret_cast<const float4*>(pk + (size_t)(k0 + r) * 256 + h * 64 + dq * 4);
    sKT[dq * 4 + 0][r] = b.x;
    sKT[dq * 4 + 1][r] = b.y;
    sKT[dq * 4 + 2][r] = b.z;
    sKT[dq * 4 + 3][r] = b.w;
  }
  __syncthreads();
  int ty = tid >> 4, tx = tid & 15;
  float acc[4][4] = {};
#pragma unroll 4
  for (int d = 0; d < 64; ++d) {
    float4 av = *reinterpret_cast<const float4*>(&sQT[d][ty * 4]);
    float4 bv = *reinterpret_cast<const float4*>(&sKT[d][tx * 4]);
    float a[4] = {av.x, av.y, av.z, av.w};
    float b[4] = {bv.x, bv.y, bv.z, bv.w};
#pragma unroll
    for (int i = 0; i < 4; ++i)
#pragma unroll
      for (int j = 0; j < 4; ++j) acc[i][j] = fmaf(a[i], b[j], acc[i][j]);
  }
  float4 s4 = *reinterpret_cast<const float4*>(sv + k0 + tx * 4);
#pragma unroll
  for (int i = 0; i < 4; ++i) {
    int qq = q0 + ty * 4 + i;
    size_t base = (size_t)h * 1048576 + (size_t)qq * 1024 + k0 + tx * 4;
    float4 dv = *reinterpret_cast<const float4*>(diffs + base);
    int4 mv = *reinterpret_cast<const int4*>(mask + (size_t)qq * 1024 + k0 + tx * 4);
    float l0 = mv.x ? fmaf(acc[i][0], 0.125f, dv.x) : NEGV;
    float l1 = mv.y ? fmaf(acc[i][1], 0.125f, dv.y) : NEGV;
    float l2 = mv.z ? fmaf(acc[i][2], 0.125f, dv.z) : NEGV;
    float l3 = mv.w ? fmaf(acc[i][3], 0.125f, dv.w) : NEGV;
    float tm = fmaxf(fmaxf(l0, l1), fmaxf(l2, l3));
    tm = fmaxf(tm, __shfl_xor(tm, 1));
    tm = fmaxf(tm, __shfl_xor(tm, 2));
    tm = fmaxf(tm, __shfl_xor(tm, 4));
    tm = fmaxf(tm, __shfl_xor(tm, 8));
    float e0 = mv.x ? __expf(l0 - tm) : 0.0f;
    float e1 = mv.y ? __expf(l1 - tm) : 0.0f;
    float e2 = mv.z ? __expf(l2 - tm) : 0.0f;
    float e3 = mv.w ? __expf(l3 - tm) : 0.0f;
    float ps = e0 + e1 + e2 + e3;
    float pd = e0 * s4.x + e1 * s4.y + e2 * s4.z + e3 * s4.w;
    ps += __shfl_xor(ps, 1); pd += __shfl_xor(pd, 1);
    ps += __shfl_xor(ps, 2); pd += __shfl_xor(pd, 2);
    ps += __shfl_xor(ps, 4); pd += __shfl_xor(pd, 4);
    ps += __shfl_xor(ps, 8); pd += __shfl_xor(pd, 8);
    if (tx == 0) {
      int plane = (h * 16 + blockIdx.x) * 1024 + qq;
      mpart[plane] = tm;
      spart[plane] = ps;
      dpart[plane] = pd;
    }
  }
}

// ---------------- merge per-tile softmax partials -> vals_mean ----------------
__global__ void vm_reduce(const float* __restrict__ mpart,
                          const float* __restrict__ spart,
                          const float* __restrict__ dpart,
                          float* __restrict__ vm) {
  int q = blockIdx.x * 256 + threadIdx.x;
  float accum = 0.0f;
#pragma unroll
  for (int h = 0; h < 4; ++h) {
    float M = -3e38f;
#pragma unroll
    for (int kb = 0; kb < 16; ++kb)
      M = fmaxf(M, mpart[(h * 16 + kb) * 1024 + q]);
    float s = 0.0f, d = 0.0f;
#pragma unroll
    for (int kb = 0; kb < 16; ++kb) {
      int p = (h * 16 + kb) * 1024 + q;
      float sc = __expf(mpart[p] - M);
      s = fmaf(spart[p], sc, s);
      d = fmaf(dpart[p], sc, d);
    }
    accum += d / s;
  }
  vm[q] = accum * (1.0f / 1024.0f);
}

extern "C" void kernel_launch(void* const* d_in, const int* in_sizes, int n_in,
                              void* d_out, int out_size, void* d_ws, size_t ws_size,
                              hipStream_t stream) {
  const float* q     = (const float*)d_in[0];
  const float* k     = (const float*)d_in[1];
  const float* v     = (const float*)d_in[2];
  const float* bias  = (const float*)d_in[3];
  const int*   mask  = (const int*)d_in[4];
  const float* Wq    = (const float*)d_in[5];
  const float* bq    = (const float*)d_in[6];
  const float* Wk    = (const float*)d_in[7];
  const float* bk    = (const float*)d_in[8];
  const float* Wbias = (const float*)d_in[9];
  const float* bbias = (const float*)d_in[10];
  const float* Wqo   = (const float*)d_in[11];
  const float* bqo   = (const float*)d_in[12];
  const float* Wko   = (const float*)d_in[13];
  const float* bko   = (const float*)d_in[14];
  const float* g_q   = (const float*)d_in[15];
  const float* be_q  = (const float*)d_in[16];
  const float* g_k   = (const float*)d_in[17];
  const float* be_k  = (const float*)d_in[18];
  const float* Wbo   = (const float*)d_in[19];
  const float* bbo   = (const float*)d_in[20];

  float* out = (float*)d_out;
  float* ws  = (float*)d_ws;
  float* projq = ws;                 // 1024x256
  float* projk = ws + 262144;        // 1024x256
  float* qo    = ws + 524288;        // 1024x256
  float* ko    = ws + 786432;        // 1024x256
  float* diffs = ws + 1048576;       // 4 x 1024 x 1024
  float* svec  = ws + 5242880;       // 1024
  float* Mmat  = ws + 5243904;       // 41 x 40 composite
  float* mpart = ws + 5246976;       // 64 x 1024
  float* spart = ws + 5312512;       // 64 x 1024
  float* dpart = ws + 5378048;       // 64 x 1024

  float* q_out    = out;             // 1024x256
  float* k_out    = out + 262144;    // 1024x256
  float* vmean    = out + 524288;    // 1024
  float* bias_out = out + 525312;    // 1024x1024x40

  prep_kernel<<<1065, 64, 0, stream>>>(v, svec, Wbias, bbias, Wbo, Mmat);
  gemm_mfma_pair<<<dim3(4, 16, 2), 256, 0, stream>>>(q, Wq, bq, projq,
                                                     k, Wk, bk, projk, 0);
  bias_mfma<<<1024, 256, 0, stream>>>(bias, Wbias, bbias, Mmat, bbo, diffs, bias_out);
  gemm_mfma_pair<<<dim3(4, 16, 2), 256, 0, stream>>>(projq, Wqo, bqo, qo,
                                                     projk, Wko, bko, ko, 1);
  ln_pair<<<dim3(1024, 2), 256, 0, stream>>>(q, qo, g_q, be_q, q_out,
                                             k, ko, g_k, be_k, k_out);
  qk_softmax<<<dim3(16, 16, 4), 256, 0, stream>>>(projq, projk, mask, diffs,
                                                  svec, mpart, spart, dpart);
  vm_reduce<<<4, 256, 0, stream>>>(mpart, spart, dpart, vmean);
}